// Round 1
// baseline (2237.734 us; speedup 1.0000x reference)
//
#include <hip/hip_runtime.h>
#include <hip/hip_bf16.h>

#define EPS_BN 1e-5f

// ================= graph preprocessing =================

__global__ void count_kernel(const int* __restrict__ dst, int* __restrict__ cnt, int E) {
  int e = blockIdx.x * blockDim.x + threadIdx.x;
  if (e < E) atomicAdd(&cnt[dst[e]], 1);
}

__global__ void dis_kernel(const int* __restrict__ cnt, float* __restrict__ dis, int n) {
  int i = blockIdx.x * blockDim.x + threadIdx.x;
  if (i < n) dis[i] = rsqrtf((float)cnt[i] + 1.0f);
}

// single-block exclusive scan over cnt -> rowstart[0..n], rowstart[n] = total
__global__ void scan_kernel(const int* __restrict__ cnt, int* __restrict__ rowstart, int n) {
  __shared__ int sdata[1024];
  __shared__ int srun;
  int tid = threadIdx.x;
  if (tid == 0) srun = 0;
  __syncthreads();
  for (int base = 0; base < n; base += 1024) {
    int i = base + tid;
    int v = (i < n) ? cnt[i] : 0;
    sdata[tid] = v;
    __syncthreads();
    for (int off = 1; off < 1024; off <<= 1) {
      int t = (tid >= off) ? sdata[tid - off] : 0;
      __syncthreads();
      sdata[tid] += t;
      __syncthreads();
    }
    int run = srun;
    if (i < n) rowstart[i] = run + sdata[tid] - v;  // exclusive
    __syncthreads();
    if (tid == 0) srun = run + sdata[1023];
    __syncthreads();
  }
  if (tid == 0) rowstart[n] = srun;
}

__global__ void scatter_kernel(const int* __restrict__ src, const int* __restrict__ dst,
                               const int* __restrict__ rowstart, int* __restrict__ cursor,
                               const float* __restrict__ dis,
                               int* __restrict__ csr_src, float* __restrict__ csr_w, int E) {
  int e = blockIdx.x * blockDim.x + threadIdx.x;
  if (e < E) {
    int d = dst[e], s = src[e];
    int p = rowstart[d] + atomicAdd(&cursor[d], 1);
    csr_src[p] = s;
    csr_w[p] = dis[s] * dis[d];
  }
}

// ================= fp32 tiled GEMM: C[Nr,F] = A[Nr,K] @ W[K,F] =================
// 64x64 block tile, BK=16, 256 threads, 4x4 register tile per thread.
__global__ __launch_bounds__(256) void gemm_kernel(
    const float* __restrict__ A, const float* __restrict__ W,
    float* __restrict__ C, int Nr, int K, int F) {
  __shared__ float As[16][68];  // [k][row], row-stride 68 floats (16B-aligned rows)
  __shared__ float Ws[16][68];  // [k][col]
  int tid = (int)threadIdx.x;
  int tx = tid & 15, ty = tid >> 4;
  int rowBase = blockIdx.x * 64;
  int colBase = blockIdx.y * 64;
  float acc[4][4] = {{0.f}};

  for (int k0 = 0; k0 < K; k0 += 16) {
    int c = tid & 15, r0 = tid >> 4;
#pragma unroll
    for (int p = 0; p < 4; ++p) {
      int r = r0 + p * 16;
      int grow = rowBase + r;
      As[c][r] = (grow < Nr) ? A[(size_t)grow * K + k0 + c] : 0.0f;
    }
    int c2 = tid & 63, kk0 = tid >> 6;
#pragma unroll
    for (int p = 0; p < 4; ++p) {
      int kk = kk0 + p * 4;
      Ws[kk][c2] = W[(size_t)(k0 + kk) * F + colBase + c2];
    }
    __syncthreads();
#pragma unroll
    for (int kk = 0; kk < 16; ++kk) {
      float4 a = *(const float4*)&As[kk][ty * 4];
      float4 w = *(const float4*)&Ws[kk][tx * 4];
      acc[0][0] += a.x * w.x; acc[0][1] += a.x * w.y; acc[0][2] += a.x * w.z; acc[0][3] += a.x * w.w;
      acc[1][0] += a.y * w.x; acc[1][1] += a.y * w.y; acc[1][2] += a.y * w.z; acc[1][3] += a.y * w.w;
      acc[2][0] += a.z * w.x; acc[2][1] += a.z * w.y; acc[2][2] += a.z * w.z; acc[2][3] += a.z * w.w;
      acc[3][0] += a.w * w.x; acc[3][1] += a.w * w.y; acc[3][2] += a.w * w.z; acc[3][3] += a.w * w.w;
    }
    __syncthreads();
  }
#pragma unroll
  for (int i = 0; i < 4; ++i) {
    int row = rowBase + ty * 4 + i;
    if (row < Nr) {
      float4 o = make_float4(acc[i][0], acc[i][1], acc[i][2], acc[i][3]);
      *(float4*)&C[(size_t)row * F + colBase + tx * 4] = o;
    }
  }
}

// ================= aggregation: H[d] = sum_in w*T[src] + dis[d]^2*T[d] + b =================
// one wave (64 lanes) per dst node; lane = feature (FD = F/64 features per lane)
template <int FD>
__global__ __launch_bounds__(256) void agg_kernel(
    const float* __restrict__ T, const int* __restrict__ rowstart,
    const int* __restrict__ csr_src, const float* __restrict__ csr_w,
    const float* __restrict__ dis, const float* __restrict__ bias,
    float* __restrict__ H, int Nn, int F) {
  int gt = blockIdx.x * blockDim.x + (int)threadIdx.x;
  int wid = gt >> 6;
  int lane = (int)threadIdx.x & 63;
  if (wid >= Nn) return;
  int d = wid;
  float dd = dis[d];
  float selfw = dd * dd;
  float acc[FD];
#pragma unroll
  for (int j = 0; j < FD; ++j) acc[j] = selfw * T[(size_t)d * F + lane + j * 64];
  int e0 = rowstart[d], e1 = rowstart[d + 1];
  for (int e = e0; e < e1; ++e) {
    int s = csr_src[e];
    float w = csr_w[e];
#pragma unroll
    for (int j = 0; j < FD; ++j) acc[j] += w * T[(size_t)s * F + lane + j * 64];
  }
#pragma unroll
  for (int j = 0; j < FD; ++j)
    H[(size_t)d * F + lane + j * 64] = acc[j] + bias[lane + j * 64];
}

// ================= BN stats over relu(H): sum & sumsq per column =================
__global__ __launch_bounds__(256) void stat_kernel(const float* __restrict__ H,
                                                   float* __restrict__ stats, int Nn, int F) {
  int tid = (int)threadIdx.x;
  int c = tid & (F - 1);          // F is a power of two (64/128/256)
  int rg = tid / F;
  int RP = 256 / F;
  float s = 0.f, sq = 0.f;
  for (int r = blockIdx.x * RP + rg; r < Nn; r += gridDim.x * RP) {
    float v = H[(size_t)r * F + c];
    v = fmaxf(v, 0.f);
    s += v;
    sq += v * v;
  }
  __shared__ float ls[256], lq[256];
  ls[tid] = s; lq[tid] = sq;
  __syncthreads();
  for (int str = 128; str >= F; str >>= 1) {
    if (tid < str) { ls[tid] += ls[tid + str]; lq[tid] += lq[tid + str]; }
    __syncthreads();
  }
  if (tid < F) {
    atomicAdd(&stats[c], ls[tid]);
    atomicAdd(&stats[256 + c], lq[tid]);
  }
}

__global__ void bnfin_kernel(const float* __restrict__ stats, const float* __restrict__ g,
                             const float* __restrict__ beta, float* __restrict__ ss,
                             int Nn, int F) {
  int c = (int)threadIdx.x;
  if (c >= F) return;
  float mean = stats[c] / (float)Nn;
  float var = stats[256 + c] / (float)Nn - mean * mean;
  float sc = g[c] * rsqrtf(var + EPS_BN);
  ss[c] = sc;
  ss[256 + c] = beta[c] - mean * sc;
}

__global__ void bnapply_kernel(float* __restrict__ H, const float* __restrict__ ss,
                               size_t total, int F) {
  size_t i = (size_t)blockIdx.x * blockDim.x + threadIdx.x;
  size_t stride = (size_t)gridDim.x * blockDim.x;
  for (; i < total; i += stride) {
    int c = (int)(i & (size_t)(F - 1));  // F power of two
    float v = fmaxf(H[i], 0.f);
    H[i] = v * ss[c] + ss[256 + c];
  }
}

// ================= classifier: out[N,10] = H[N,64] @ Wc[64,10] + bc =================
// one wave per row; lane k holds H[row,k]; wave-reduce per class.
__global__ __launch_bounds__(256) void cls_kernel(const float* __restrict__ H,
                                                  const float* __restrict__ Wc,
                                                  const float* __restrict__ bc,
                                                  float* __restrict__ out, int Nn) {
  int gt = blockIdx.x * blockDim.x + (int)threadIdx.x;
  int wid = gt >> 6;
  int lane = (int)threadIdx.x & 63;
  if (wid >= Nn) return;
  float v = H[(size_t)wid * 64 + lane];
#pragma unroll
  for (int c = 0; c < 10; ++c) {
    float p = v * Wc[lane * 10 + c];
#pragma unroll
    for (int off = 32; off > 0; off >>= 1) p += __shfl_down(p, off, 64);
    if (lane == 0) out[(size_t)wid * 10 + c] = p + bc[c];
  }
}

// ================= host launch =================

extern "C" void kernel_launch(void* const* d_in, const int* in_sizes, int n_in,
                              void* d_out, int out_size, void* d_ws, size_t ws_size,
                              hipStream_t stream) {
  (void)n_in; (void)out_size; (void)ws_size;
  const float* x     = (const float*)d_in[0];
  const int*   edge  = (const int*)d_in[1];
  const int E  = in_sizes[1] / 2;
  const int Nn = in_sizes[0] / 512;
  const int* e_src = edge;
  const int* e_dst = edge + E;

  const float* W[4]  = {(const float*)d_in[2],  (const float*)d_in[6],
                        (const float*)d_in[10], (const float*)d_in[14]};
  const float* bv[4] = {(const float*)d_in[3],  (const float*)d_in[7],
                        (const float*)d_in[11], (const float*)d_in[15]};
  const float* gv[4] = {(const float*)d_in[4],  (const float*)d_in[8],
                        (const float*)d_in[12], (const float*)d_in[16]};
  const float* bt[4] = {(const float*)d_in[5],  (const float*)d_in[9],
                        (const float*)d_in[13], (const float*)d_in[17]};
  const float* Wc = (const float*)d_in[18];
  const float* bc = (const float*)d_in[19];
  float* out = (float*)d_out;

  // workspace layout (256B aligned blocks)
  char* p = (char*)d_ws;
  auto alloc = [&](size_t bytes) -> void* {
    void* r = (void*)p;
    p += (bytes + 255) & ~(size_t)255;
    return r;
  };
  int*   cnt      = (int*)alloc((size_t)Nn * 4);
  int*   cursor   = (int*)alloc((size_t)Nn * 4);
  int*   rowstart = (int*)alloc((size_t)(Nn + 1) * 4);
  float* dis      = (float*)alloc((size_t)Nn * 4);
  float* stats    = (float*)alloc(512 * 4);
  float* ss       = (float*)alloc(512 * 4);
  int*   csr_src  = (int*)alloc((size_t)E * 4);
  float* csr_w    = (float*)alloc((size_t)E * 4);
  float* B0       = (float*)alloc((size_t)Nn * 256 * 4);
  float* B1       = (float*)alloc((size_t)Nn * 256 * 4);
  float* B2       = (float*)alloc((size_t)Nn * 256 * 4);

  // zero the atomic counters (ws is poisoned 0xAA before every launch)
  hipMemsetAsync(cnt, 0, (size_t)Nn * 4, stream);
  hipMemsetAsync(cursor, 0, (size_t)Nn * 4, stream);

  // graph prep
  count_kernel<<<(E + 255) / 256, 256, 0, stream>>>(e_dst, cnt, E);
  dis_kernel<<<(Nn + 255) / 256, 256, 0, stream>>>(cnt, dis, Nn);
  scan_kernel<<<1, 1024, 0, stream>>>(cnt, rowstart, Nn);
  scatter_kernel<<<(E + 255) / 256, 256, 0, stream>>>(e_src, e_dst, rowstart, cursor,
                                                      dis, csr_src, csr_w, E);

  auto layer = [&](const float* Hin, int K, int F, const float* Wl, const float* bl,
                   const float* gl, const float* betal, float* T, float* Hb) {
    dim3 ggrid((Nn + 63) / 64, F / 64);
    gemm_kernel<<<ggrid, 256, 0, stream>>>(Hin, Wl, T, Nn, K, F);
    int aggBlocks = (Nn * 64 + 255) / 256;
    switch (F / 64) {
      case 1: agg_kernel<1><<<aggBlocks, 256, 0, stream>>>(T, rowstart, csr_src, csr_w, dis, bl, Hb, Nn, F); break;
      case 2: agg_kernel<2><<<aggBlocks, 256, 0, stream>>>(T, rowstart, csr_src, csr_w, dis, bl, Hb, Nn, F); break;
      default: agg_kernel<4><<<aggBlocks, 256, 0, stream>>>(T, rowstart, csr_src, csr_w, dis, bl, Hb, Nn, F); break;
    }
    hipMemsetAsync(stats, 0, 512 * 4, stream);
    stat_kernel<<<1024, 256, 0, stream>>>(Hb, stats, Nn, F);
    bnfin_kernel<<<1, 256, 0, stream>>>(stats, gl, betal, ss, Nn, F);
    size_t total = (size_t)Nn * F;
    int ablocks = (int)((total + 255) / 256);
    bnapply_kernel<<<ablocks, 256, 0, stream>>>(Hb, ss, total, F);
  };

  // L1: x[N,512] -> B1[N,128]   (T=B0)
  layer(x,  512, 128, W[0], bv[0], gv[0], bt[0], B0, B1);
  // L2: B1[N,128] -> B0[N,256]  (T=B2)
  layer(B1, 128, 256, W[1], bv[1], gv[1], bt[1], B2, B0);
  // L3: B0[N,256] -> B2[N,128]  (T=B1)
  layer(B0, 256, 128, W[2], bv[2], gv[2], bt[2], B1, B2);
  // L4: B2[N,128] -> B1[N,64]   (T=B0)
  layer(B2, 128,  64, W[3], bv[3], gv[3], bt[3], B0, B1);

  // classifier
  int clsBlocks = (Nn * 64 + 255) / 256;
  cls_kernel<<<clsBlocks, 256, 0, stream>>>(B1, Wc, bc, out, Nn);
}

// Round 2
// 1555.317 us; speedup vs baseline: 1.4388x; 1.4388x over previous
//
#include <hip/hip_runtime.h>
#include <hip/hip_bf16.h>

#define EPS_BN 1e-5f

using frag8 = __attribute__((ext_vector_type(8))) short;   // 8 bf16 (4 VGPRs)
using f32x4 = __attribute__((ext_vector_type(4))) float;   // 4 fp32 acc

typedef const __attribute__((address_space(1))) void* gas_ptr;
typedef __attribute__((address_space(3))) void* las_ptr;

__device__ __forceinline__ void async_ld16(const void* g, void* l) {
  __builtin_amdgcn_global_load_lds((gas_ptr)g, (las_ptr)l, 16, 0, 0);
}

// ================= graph preprocessing =================

__global__ void count_kernel(const int* __restrict__ dst, int* __restrict__ cnt, int E) {
  int e = blockIdx.x * blockDim.x + threadIdx.x;
  if (e < E) atomicAdd(&cnt[dst[e]], 1);
}

__global__ void dis_kernel(const int* __restrict__ cnt, float* __restrict__ dis, int n) {
  int i = blockIdx.x * blockDim.x + threadIdx.x;
  if (i < n) dis[i] = rsqrtf((float)cnt[i] + 1.0f);
}

// hierarchical exclusive scan: phase1 per-block scan + block sums
__global__ void scan1_kernel(const int* __restrict__ cnt, int* __restrict__ out,
                             int* __restrict__ bsum, int n) {
  __shared__ int sdata[1024];
  int tid = threadIdx.x;
  int i = blockIdx.x * 1024 + tid;
  int v = (i < n) ? cnt[i] : 0;
  sdata[tid] = v;
  __syncthreads();
  for (int off = 1; off < 1024; off <<= 1) {
    int t = (tid >= off) ? sdata[tid - off] : 0;
    __syncthreads();
    sdata[tid] += t;
    __syncthreads();
  }
  if (i < n) out[i] = sdata[tid] - v;  // exclusive within block
  if (tid == 1023) bsum[blockIdx.x] = sdata[1023];
}

// phase2: single block exclusive scan of block sums (nb <= 1024)
__global__ void scan2_kernel(int* __restrict__ bsum, int nb) {
  __shared__ int sdata[1024];
  int tid = threadIdx.x;
  int v = (tid < nb) ? bsum[tid] : 0;
  sdata[tid] = v;
  __syncthreads();
  for (int off = 1; off < 1024; off <<= 1) {
    int t = (tid >= off) ? sdata[tid - off] : 0;
    __syncthreads();
    sdata[tid] += t;
    __syncthreads();
  }
  if (tid < nb) bsum[tid] = sdata[tid] - v;
}

// phase3: add block offsets; rowstart[n] = E (every edge lands somewhere)
__global__ void scan3_kernel(int* __restrict__ out, const int* __restrict__ bsum,
                             int n, int E) {
  int i = blockIdx.x * 1024 + threadIdx.x;
  if (i < n) out[i] += bsum[blockIdx.x];
  if (i == 0) out[n] = E;
}

__global__ void scatter_kernel(const int* __restrict__ src, const int* __restrict__ dst,
                               const int* __restrict__ rowstart, int* __restrict__ cursor,
                               const float* __restrict__ dis,
                               int* __restrict__ csr_src, float* __restrict__ csr_w, int E) {
  int e = blockIdx.x * blockDim.x + threadIdx.x;
  if (e < E) {
    int d = dst[e], s = src[e];
    int p = rowstart[d] + atomicAdd(&cursor[d], 1);
    csr_src[p] = s;
    csr_w[p] = dis[s] * dis[d];
  }
}

// ================= conversions =================

__global__ void convert_bf16_kernel(const float* __restrict__ in,
                                    __hip_bfloat16* __restrict__ out, size_t n4) {
  size_t i = (size_t)blockIdx.x * blockDim.x + threadIdx.x;
  size_t stride = (size_t)gridDim.x * blockDim.x;
  for (; i < n4; i += stride) {
    float4 v = *(const float4*)&in[i * 4];
    union { ushort4 u; __hip_bfloat16 h[4]; } pk;
    pk.h[0] = __float2bfloat16(v.x);
    pk.h[1] = __float2bfloat16(v.y);
    pk.h[2] = __float2bfloat16(v.z);
    pk.h[3] = __float2bfloat16(v.w);
    *(ushort4*)&out[i * 4] = pk.u;
  }
}

// Wt[f][k] = bf16(W[k][f])
__global__ void wtrans_kernel(const float* __restrict__ W, __hip_bfloat16* __restrict__ Wt,
                              int K, int F) {
  int i = blockIdx.x * blockDim.x + threadIdx.x;
  if (i < K * F) {
    int k = i / F, f = i % F;
    Wt[f * K + k] = __float2bfloat16(W[i]);
  }
}

// ================= bf16 MFMA GEMM: C[Nr,F] = A[Nr,K] @ Bt[F,K]^T =================
// 128 x TN block tile, BK=32, 256 threads (4 waves). m97 structure:
// global_load_lds width=16 staging, ds_read_b128 fragments, 16x16x32 MFMA.
template <int TN>  // 128 or 64
__global__ __launch_bounds__(256) void mfma_gemm_kernel(
    const __hip_bfloat16* __restrict__ A, const __hip_bfloat16* __restrict__ Bt,
    __hip_bfloat16* __restrict__ C, int Nr, int K, int F) {
  constexpr int WM = (TN == 128) ? 64 : 32;  // wave tile rows
  constexpr int MI = WM / 16;                // m-frags per wave (4 or 2)
  __shared__ __align__(16) __hip_bfloat16 As[128 * 32];
  __shared__ __align__(16) __hip_bfloat16 Bs[TN * 32];
  int tid = (int)threadIdx.x;
  int wid = tid >> 6, lane = tid & 63;
  int rowBase = blockIdx.x * 128;
  int colBase = blockIdx.y * TN;
  int wr, wc;
  if (TN == 128) { wr = (wid >> 1) * 64; wc = (wid & 1) * 64; }
  else           { wr = wid * 32;        wc = 0; }

  f32x4 zero = {0.f, 0.f, 0.f, 0.f};
  f32x4 acc[MI][4];
#pragma unroll
  for (int i = 0; i < MI; ++i)
#pragma unroll
    for (int j = 0; j < 4; ++j) acc[i][j] = zero;

  int lm = lane & 15;
  int k8 = (lane >> 4) * 8;

  for (int k0 = 0; k0 < K; k0 += 32) {
    // stage A tile [128 rows][32 k] row-major (64 B/row), 2 passes x 256 lanes x 16 B
#pragma unroll
    for (int p = 0; p < 2; ++p) {
      int sidx = p * 256 + tid;
      int row = sidx >> 2;
      int kq = (sidx & 3) * 8;
      int gr = rowBase + row;
      if (gr >= Nr) gr = Nr - 1;
      async_ld16(A + (size_t)gr * K + k0 + kq, (char*)As + (p * 256 + wid * 64) * 16);
    }
    // stage B tile [TN cols][32 k]
    constexpr int BPASS = TN / 64;
#pragma unroll
    for (int p = 0; p < BPASS; ++p) {
      int sidx = p * 256 + tid;
      int col = sidx >> 2;
      int kq = (sidx & 3) * 8;
      async_ld16(Bt + (size_t)(colBase + col) * K + k0 + kq,
                 (char*)Bs + (p * 256 + wid * 64) * 16);
    }
    __syncthreads();  // compiler emits vmcnt(0) drain before barrier

    frag8 af[MI], bf[4];
#pragma unroll
    for (int i = 0; i < MI; ++i)
      af[i] = *(const frag8*)&As[(wr + i * 16 + lm) * 32 + k8];
#pragma unroll
    for (int j = 0; j < 4; ++j)
      bf[j] = *(const frag8*)&Bs[(wc + j * 16 + lm) * 32 + k8];
#pragma unroll
    for (int i = 0; i < MI; ++i)
#pragma unroll
      for (int j = 0; j < 4; ++j)
        acc[i][j] = __builtin_amdgcn_mfma_f32_16x16x32_bf16(af[i], bf[j], acc[i][j], 0, 0, 0);
    __syncthreads();
  }

  // epilogue: C/D layout col=lane&15, row=(lane>>4)*4+reg  [verified m89]
  int rquad = (lane >> 4) * 4;
#pragma unroll
  for (int i = 0; i < MI; ++i) {
    int rb = rowBase + wr + i * 16 + rquad;
#pragma unroll
    for (int r = 0; r < 4; ++r) {
      int row = rb + r;
      if (row < Nr) {
#pragma unroll
        for (int j = 0; j < 4; ++j) {
          int col = colBase + wc + j * 16 + lm;
          C[(size_t)row * F + col] = __float2bfloat16(acc[i][j][r]);
        }
      }
    }
  }
}

// ================= aggregation: H[d] = sum_in w*T[src] + dis[d]^2*T[d] + b =================
// one wave per dst node; lane = feature; T is bf16, accumulate fp32, H fp32.
template <int FD>
__global__ __launch_bounds__(256) void agg_kernel(
    const __hip_bfloat16* __restrict__ T, const int* __restrict__ rowstart,
    const int* __restrict__ csr_src, const float* __restrict__ csr_w,
    const float* __restrict__ dis, const float* __restrict__ bias,
    float* __restrict__ H, int Nn, int F) {
  int gt = blockIdx.x * blockDim.x + (int)threadIdx.x;
  int wid = gt >> 6;
  int lane = (int)threadIdx.x & 63;
  if (wid >= Nn) return;
  int d = wid;
  float dd = dis[d];
  float selfw = dd * dd;
  float acc[FD];
#pragma unroll
  for (int j = 0; j < FD; ++j)
    acc[j] = selfw * __bfloat162float(T[(size_t)d * F + lane + j * 64]);
  int e0 = rowstart[d], e1 = rowstart[d + 1];
  for (int e = e0; e < e1; ++e) {
    int s = csr_src[e];
    float w = csr_w[e];
#pragma unroll
    for (int j = 0; j < FD; ++j)
      acc[j] += w * __bfloat162float(T[(size_t)s * F + lane + j * 64]);
  }
#pragma unroll
  for (int j = 0; j < FD; ++j)
    H[(size_t)d * F + lane + j * 64] = acc[j] + bias[lane + j * 64];
}

// ================= BN stats over relu(H): sum & sumsq per column =================
__global__ __launch_bounds__(256) void stat_kernel(const float* __restrict__ H,
                                                   float* __restrict__ stats, int Nn, int F) {
  int tid = (int)threadIdx.x;
  int c = tid & (F - 1);
  int rg = tid / F;
  int RP = 256 / F;
  float s = 0.f, sq = 0.f;
  for (int r = blockIdx.x * RP + rg; r < Nn; r += gridDim.x * RP) {
    float v = H[(size_t)r * F + c];
    v = fmaxf(v, 0.f);
    s += v;
    sq += v * v;
  }
  __shared__ float ls[256], lq[256];
  ls[tid] = s; lq[tid] = sq;
  __syncthreads();
  for (int str = 128; str >= F; str >>= 1) {
    if (tid < str) { ls[tid] += ls[tid + str]; lq[tid] += lq[tid + str]; }
    __syncthreads();
  }
  if (tid < F) {
    atomicAdd(&stats[c], ls[tid]);
    atomicAdd(&stats[256 + c], lq[tid]);
  }
}

__global__ void bnfin_kernel(const float* __restrict__ stats, const float* __restrict__ g,
                             const float* __restrict__ beta, float* __restrict__ ss,
                             int Nn, int F) {
  int c = (int)threadIdx.x;
  if (c >= F) return;
  float mean = stats[c] / (float)Nn;
  float var = stats[256 + c] / (float)Nn - mean * mean;
  float sc = g[c] * rsqrtf(var + EPS_BN);
  ss[c] = sc;
  ss[256 + c] = beta[c] - mean * sc;
}

// relu+BN apply, fp32 in -> bf16 out (next layer's GEMM input)
__global__ void bnapply_kernel(const float* __restrict__ H, const float* __restrict__ ss,
                               __hip_bfloat16* __restrict__ O, size_t total4, int F) {
  size_t i = (size_t)blockIdx.x * blockDim.x + threadIdx.x;
  size_t stride = (size_t)gridDim.x * blockDim.x;
  for (; i < total4; i += stride) {
    size_t b = i * 4;
    float4 v = *(const float4*)&H[b];
    int c = (int)(b & (size_t)(F - 1));
    union { ushort4 u; __hip_bfloat16 h[4]; } pk;
    pk.h[0] = __float2bfloat16(fmaxf(v.x, 0.f) * ss[c + 0] + ss[256 + c + 0]);
    pk.h[1] = __float2bfloat16(fmaxf(v.y, 0.f) * ss[c + 1] + ss[256 + c + 1]);
    pk.h[2] = __float2bfloat16(fmaxf(v.z, 0.f) * ss[c + 2] + ss[256 + c + 2]);
    pk.h[3] = __float2bfloat16(fmaxf(v.w, 0.f) * ss[c + 3] + ss[256 + c + 3]);
    *(ushort4*)&O[b] = pk.u;
  }
}

// ================= classifier: out[N,10] = H[N,64] @ Wc[64,10] + bc =================
__global__ __launch_bounds__(256) void cls_kernel(const __hip_bfloat16* __restrict__ H,
                                                  const float* __restrict__ Wc,
                                                  const float* __restrict__ bc,
                                                  float* __restrict__ out, int Nn) {
  int gt = blockIdx.x * blockDim.x + (int)threadIdx.x;
  int wid = gt >> 6;
  int lane = (int)threadIdx.x & 63;
  if (wid >= Nn) return;
  float v = __bfloat162float(H[(size_t)wid * 64 + lane]);
#pragma unroll
  for (int c = 0; c < 10; ++c) {
    float p = v * Wc[lane * 10 + c];
#pragma unroll
    for (int off = 32; off > 0; off >>= 1) p += __shfl_down(p, off, 64);
    if (lane == 0) out[(size_t)wid * 10 + c] = p + bc[c];
  }
}

// ================= host launch =================

extern "C" void kernel_launch(void* const* d_in, const int* in_sizes, int n_in,
                              void* d_out, int out_size, void* d_ws, size_t ws_size,
                              hipStream_t stream) {
  (void)n_in; (void)out_size; (void)ws_size;
  const float* x    = (const float*)d_in[0];
  const int*   edge = (const int*)d_in[1];
  const int E  = in_sizes[1] / 2;
  const int Nn = in_sizes[0] / 512;
  const int* e_src = edge;
  const int* e_dst = edge + E;

  const float* W[4]  = {(const float*)d_in[2],  (const float*)d_in[6],
                        (const float*)d_in[10], (const float*)d_in[14]};
  const float* bv[4] = {(const float*)d_in[3],  (const float*)d_in[7],
                        (const float*)d_in[11], (const float*)d_in[15]};
  const float* gv[4] = {(const float*)d_in[4],  (const float*)d_in[8],
                        (const float*)d_in[12], (const float*)d_in[16]};
  const float* bt[4] = {(const float*)d_in[5],  (const float*)d_in[9],
                        (const float*)d_in[13], (const float*)d_in[17]};
  const float* Wc = (const float*)d_in[18];
  const float* bc = (const float*)d_in[19];
  float* out = (float*)d_out;

  const int Kdim[4] = {512, 128, 256, 128};
  const int Fdim[4] = {128, 256, 128, 64};

  // workspace layout
  char* p = (char*)d_ws;
  auto alloc = [&](size_t bytes) -> void* {
    void* r = (void*)p;
    p += (bytes + 255) & ~(size_t)255;
    return r;
  };
  int*   cnt      = (int*)alloc((size_t)Nn * 4);
  int*   cursor   = (int*)alloc((size_t)Nn * 4);
  int*   rowstart = (int*)alloc((size_t)(Nn + 1) * 4);
  int*   bsum     = (int*)alloc(1024 * 4);
  float* dis      = (float*)alloc((size_t)Nn * 4);
  float* stats    = (float*)alloc(512 * 4);
  float* ss       = (float*)alloc(512 * 4);
  int*   csr_src  = (int*)alloc((size_t)E * 4);
  float* csr_w    = (float*)alloc((size_t)E * 4);
  __hip_bfloat16* Wt[4];
  for (int l = 0; l < 4; ++l)
    Wt[l] = (__hip_bfloat16*)alloc((size_t)Kdim[l] * Fdim[l] * 2);
  // R0: x_bf16 [Nn*512]*2B during GEMM1, then reused as fp32 H [Nn*256]*4B
  char* R0 = (char*)alloc((size_t)Nn * 512 * 2);
  __hip_bfloat16* Tb = (__hip_bfloat16*)alloc((size_t)Nn * 256 * 2);
  __hip_bfloat16* P0 = (__hip_bfloat16*)alloc((size_t)Nn * 256 * 2);
  __hip_bfloat16* P1 = (__hip_bfloat16*)alloc((size_t)Nn * 256 * 2);
  __hip_bfloat16* Xb = (__hip_bfloat16*)R0;
  float*          Hf = (float*)R0;

  hipMemsetAsync(cnt, 0, (size_t)Nn * 4, stream);
  hipMemsetAsync(cursor, 0, (size_t)Nn * 4, stream);

  // graph prep
  int nb = (Nn + 1023) / 1024;
  count_kernel<<<(E + 255) / 256, 256, 0, stream>>>(e_dst, cnt, E);
  dis_kernel<<<(Nn + 255) / 256, 256, 0, stream>>>(cnt, dis, Nn);
  scan1_kernel<<<nb, 1024, 0, stream>>>(cnt, rowstart, bsum, Nn);
  scan2_kernel<<<1, 1024, 0, stream>>>(bsum, nb);
  scan3_kernel<<<nb, 1024, 0, stream>>>(rowstart, bsum, Nn, E);
  scatter_kernel<<<(E + 255) / 256, 256, 0, stream>>>(e_src, e_dst, rowstart, cursor,
                                                      dis, csr_src, csr_w, E);

  // weight transposes (bf16) + x conversion
  for (int l = 0; l < 4; ++l) {
    int kf = Kdim[l] * Fdim[l];
    wtrans_kernel<<<(kf + 255) / 256, 256, 0, stream>>>(W[l], Wt[l], Kdim[l], Fdim[l]);
  }
  convert_bf16_kernel<<<4096, 256, 0, stream>>>(x, Xb, (size_t)Nn * 512 / 4);

  auto layer = [&](const __hip_bfloat16* Hin, int l, __hip_bfloat16* Obf) {
    int K = Kdim[l], F = Fdim[l];
    // GEMM -> Tb (bf16)
    if (F >= 128) {
      dim3 g((Nn + 127) / 128, F / 128);
      mfma_gemm_kernel<128><<<g, 256, 0, stream>>>(Hin, Wt[l], Tb, Nn, K, F);
    } else {
      dim3 g((Nn + 127) / 128, 1);
      mfma_gemm_kernel<64><<<g, 256, 0, stream>>>(Hin, Wt[l], Tb, Nn, K, F);
    }
    // aggregation -> Hf (fp32)
    int aggBlocks = (Nn * 64 + 255) / 256;
    switch (F / 64) {
      case 1: agg_kernel<1><<<aggBlocks, 256, 0, stream>>>(Tb, rowstart, csr_src, csr_w, dis, bv[l], Hf, Nn, F); break;
      case 2: agg_kernel<2><<<aggBlocks, 256, 0, stream>>>(Tb, rowstart, csr_src, csr_w, dis, bv[l], Hf, Nn, F); break;
      default: agg_kernel<4><<<aggBlocks, 256, 0, stream>>>(Tb, rowstart, csr_src, csr_w, dis, bv[l], Hf, Nn, F); break;
    }
    // BN
    hipMemsetAsync(stats, 0, 512 * 4, stream);
    stat_kernel<<<1024, 256, 0, stream>>>(Hf, stats, Nn, F);
    bnfin_kernel<<<1, 256, 0, stream>>>(stats, gv[l], bt[l], ss, Nn, F);
    size_t total4 = (size_t)Nn * F / 4;
    int ablocks = (int)((total4 + 255) / 256);
    bnapply_kernel<<<ablocks, 256, 0, stream>>>(Hf, ss, Obf, total4, F);
  };

  layer(Xb, 0, P0);   // L1: 512->128
  layer(P0, 1, P1);   // L2: 128->256
  layer(P1, 2, P0);   // L3: 256->128
  layer(P0, 3, P1);   // L4: 128->64

  int clsBlocks = (Nn * 64 + 255) / 256;
  cls_kernel<<<clsBlocks, 256, 0, stream>>>(P1, Wc, bc, out, Nn);
}

// Round 3
// 1244.884 us; speedup vs baseline: 1.7975x; 1.2494x over previous
//
#include <hip/hip_runtime.h>
#include <hip/hip_bf16.h>

#define EPS_BN 1e-5f

using frag8 = __attribute__((ext_vector_type(8))) short;   // 8 bf16 (4 VGPRs)
using f32x4 = __attribute__((ext_vector_type(4))) float;   // 4 fp32 acc

typedef const __attribute__((address_space(1))) void* gas_ptr;
typedef __attribute__((address_space(3))) void* las_ptr;

__device__ __forceinline__ void async_ld16(const void* g, void* l) {
  __builtin_amdgcn_global_load_lds((gas_ptr)g, (las_ptr)l, 16, 0, 0);
}

__device__ __forceinline__ float bfu2f(unsigned short u) {
  union { unsigned int i; float f; } c;
  c.i = (unsigned int)u << 16;
  return c.f;
}

// ================= graph preprocessing =================

__global__ void count_kernel(const int* __restrict__ dst, int* __restrict__ cnt, int E) {
  int e = blockIdx.x * blockDim.x + threadIdx.x;
  if (e < E) atomicAdd(&cnt[dst[e]], 1);
}

__global__ void dis_kernel(const int* __restrict__ cnt, float* __restrict__ dis, int n) {
  int i = blockIdx.x * blockDim.x + threadIdx.x;
  if (i < n) dis[i] = rsqrtf((float)cnt[i] + 1.0f);
}

// hierarchical exclusive scan
__global__ void scan1_kernel(const int* __restrict__ cnt, int* __restrict__ out,
                             int* __restrict__ bsum, int n) {
  __shared__ int sdata[1024];
  int tid = threadIdx.x;
  int i = blockIdx.x * 1024 + tid;
  int v = (i < n) ? cnt[i] : 0;
  sdata[tid] = v;
  __syncthreads();
  for (int off = 1; off < 1024; off <<= 1) {
    int t = (tid >= off) ? sdata[tid - off] : 0;
    __syncthreads();
    sdata[tid] += t;
    __syncthreads();
  }
  if (i < n) out[i] = sdata[tid] - v;
  if (tid == 1023) bsum[blockIdx.x] = sdata[1023];
}

__global__ void scan2_kernel(int* __restrict__ bsum, int nb) {
  __shared__ int sdata[1024];
  int tid = threadIdx.x;
  int v = (tid < nb) ? bsum[tid] : 0;
  sdata[tid] = v;
  __syncthreads();
  for (int off = 1; off < 1024; off <<= 1) {
    int t = (tid >= off) ? sdata[tid - off] : 0;
    __syncthreads();
    sdata[tid] += t;
    __syncthreads();
  }
  if (tid < nb) bsum[tid] = sdata[tid] - v;
}

__global__ void scan3_kernel(int* __restrict__ out, const int* __restrict__ bsum,
                             int n, int E) {
  int i = blockIdx.x * 1024 + threadIdx.x;
  if (i < n) out[i] += bsum[blockIdx.x];
  if (i == 0) out[n] = E;
}

__global__ void scatter_kernel(const int* __restrict__ src, const int* __restrict__ dst,
                               const int* __restrict__ rowstart, int* __restrict__ cursor,
                               const float* __restrict__ dis,
                               int* __restrict__ csr_src, float* __restrict__ csr_w, int E) {
  int e = blockIdx.x * blockDim.x + threadIdx.x;
  if (e < E) {
    int d = dst[e], s = src[e];
    int p = rowstart[d] + atomicAdd(&cursor[d], 1);
    csr_src[p] = s;
    csr_w[p] = dis[s] * dis[d];
  }
}

// ================= conversions =================

__global__ void convert_bf16_kernel(const float* __restrict__ in,
                                    __hip_bfloat16* __restrict__ out, size_t n4) {
  size_t i = (size_t)blockIdx.x * blockDim.x + threadIdx.x;
  size_t stride = (size_t)gridDim.x * blockDim.x;
  for (; i < n4; i += stride) {
    float4 v = *(const float4*)&in[i * 4];
    union { ushort4 u; __hip_bfloat16 h[4]; } pk;
    pk.h[0] = __float2bfloat16(v.x);
    pk.h[1] = __float2bfloat16(v.y);
    pk.h[2] = __float2bfloat16(v.z);
    pk.h[3] = __float2bfloat16(v.w);
    *(ushort4*)&out[i * 4] = pk.u;
  }
}

__global__ void wtrans_kernel(const float* __restrict__ W, __hip_bfloat16* __restrict__ Wt,
                              int K, int F) {
  int i = blockIdx.x * blockDim.x + threadIdx.x;
  if (i < K * F) {
    int k = i / F, f = i % F;
    Wt[f * K + k] = __float2bfloat16(W[i]);
  }
}

// ================= bf16 MFMA GEMM: C[Nr,F] = A[Nr,K] @ Bt[F,K]^T =================
// F32OUT: write fp32 + bias[col] (for the agg-first layer); else bf16, no bias.
template <int TN, bool F32OUT>
__global__ __launch_bounds__(256) void mfma_gemm_kernel(
    const __hip_bfloat16* __restrict__ A, const __hip_bfloat16* __restrict__ Bt,
    void* __restrict__ Cv, const float* __restrict__ bias, int Nr, int K, int F) {
  constexpr int WM = (TN == 128) ? 64 : 32;
  constexpr int MI = WM / 16;
  __shared__ __align__(16) __hip_bfloat16 As[128 * 32];
  __shared__ __align__(16) __hip_bfloat16 Bs[TN * 32];
  int tid = (int)threadIdx.x;
  int wid = tid >> 6, lane = tid & 63;
  int rowBase = blockIdx.x * 128;
  int colBase = blockIdx.y * TN;
  int wr, wc;
  if (TN == 128) { wr = (wid >> 1) * 64; wc = (wid & 1) * 64; }
  else           { wr = wid * 32;        wc = 0; }

  f32x4 zero = {0.f, 0.f, 0.f, 0.f};
  f32x4 acc[MI][4];
#pragma unroll
  for (int i = 0; i < MI; ++i)
#pragma unroll
    for (int j = 0; j < 4; ++j) acc[i][j] = zero;

  int lm = lane & 15;
  int k8 = (lane >> 4) * 8;

  for (int k0 = 0; k0 < K; k0 += 32) {
#pragma unroll
    for (int p = 0; p < 2; ++p) {
      int sidx = p * 256 + tid;
      int row = sidx >> 2;
      int kq = (sidx & 3) * 8;
      int gr = rowBase + row;
      if (gr >= Nr) gr = Nr - 1;
      async_ld16(A + (size_t)gr * K + k0 + kq, (char*)As + (p * 256 + wid * 64) * 16);
    }
    constexpr int BPASS = TN / 64;
#pragma unroll
    for (int p = 0; p < BPASS; ++p) {
      int sidx = p * 256 + tid;
      int col = sidx >> 2;
      int kq = (sidx & 3) * 8;
      async_ld16(Bt + (size_t)(colBase + col) * K + k0 + kq,
                 (char*)Bs + (p * 256 + wid * 64) * 16);
    }
    __syncthreads();

    frag8 af[MI], bf[4];
#pragma unroll
    for (int i = 0; i < MI; ++i)
      af[i] = *(const frag8*)&As[(wr + i * 16 + lm) * 32 + k8];
#pragma unroll
    for (int j = 0; j < 4; ++j)
      bf[j] = *(const frag8*)&Bs[(wc + j * 16 + lm) * 32 + k8];
#pragma unroll
    for (int i = 0; i < MI; ++i)
#pragma unroll
      for (int j = 0; j < 4; ++j)
        acc[i][j] = __builtin_amdgcn_mfma_f32_16x16x32_bf16(af[i], bf[j], acc[i][j], 0, 0, 0);
    __syncthreads();
  }

  // C/D layout: col=lane&15, row=(lane>>4)*4+reg  [verified m89]
  int rquad = (lane >> 4) * 4;
#pragma unroll
  for (int i = 0; i < MI; ++i) {
    int rb = rowBase + wr + i * 16 + rquad;
#pragma unroll
    for (int r = 0; r < 4; ++r) {
      int row = rb + r;
      if (row < Nr) {
#pragma unroll
        for (int j = 0; j < 4; ++j) {
          int col = colBase + wc + j * 16 + lm;
          if constexpr (F32OUT) {
            ((float*)Cv)[(size_t)row * F + col] = acc[i][j][r] + bias[col];
          } else {
            ((__hip_bfloat16*)Cv)[(size_t)row * F + col] = __float2bfloat16(acc[i][j][r]);
          }
        }
      }
    }
  }
}

// ================= aggregation =================
// one wave per dst node; lane owns VEC contiguous bf16 features.
// 8-wide edge unroll -> 8 independent in-flight row gathers per wave.
// OT=float: H = agg + bias (bias!=null). OT=bf16: H = bf16(agg), bias==null.
template <int VEC, typename OT>
__global__ __launch_bounds__(256) void agg_kernel(
    const __hip_bfloat16* __restrict__ T, const int* __restrict__ rowstart,
    const int* __restrict__ csr_src, const float* __restrict__ csr_w,
    const float* __restrict__ dis, const float* __restrict__ bias,
    OT* __restrict__ H, int Nn, int F) {
  int gt = blockIdx.x * blockDim.x + (int)threadIdx.x;
  int wid = gt >> 6;
  int lane = (int)threadIdx.x & 63;
  if (wid >= Nn) return;
  int d = wid;
  int off = lane * VEC;
  const unsigned short* Tu = (const unsigned short*)T;

  float dd = dis[d];
  float selfw = dd * dd;
  float acc[VEC];
  {
    unsigned short r[VEC];
    if constexpr (VEC == 2) {
      *(ushort2*)r = *(const ushort2*)&Tu[(size_t)d * F + off];
    } else {
      r[0] = Tu[(size_t)d * F + off];
    }
#pragma unroll
    for (int j = 0; j < VEC; ++j) acc[j] = selfw * bfu2f(r[j]);
  }

  int e0 = rowstart[d], e1 = rowstart[d + 1];
  int e = e0;
  for (; e + 8 <= e1; e += 8) {
    int s[8];
    float w[8];
#pragma unroll
    for (int q = 0; q < 8; ++q) { s[q] = csr_src[e + q]; w[q] = csr_w[e + q]; }
    unsigned short r[8][VEC];
#pragma unroll
    for (int q = 0; q < 8; ++q) {
      if constexpr (VEC == 2) {
        *(ushort2*)r[q] = *(const ushort2*)&Tu[(size_t)s[q] * F + off];
      } else {
        r[q][0] = Tu[(size_t)s[q] * F + off];
      }
    }
#pragma unroll
    for (int q = 0; q < 8; ++q)
#pragma unroll
      for (int j = 0; j < VEC; ++j) acc[j] += w[q] * bfu2f(r[q][j]);
  }
  for (; e < e1; ++e) {
    int s = csr_src[e];
    float w = csr_w[e];
    unsigned short r[VEC];
    if constexpr (VEC == 2) {
      *(ushort2*)r = *(const ushort2*)&Tu[(size_t)s * F + off];
    } else {
      r[0] = Tu[(size_t)s * F + off];
    }
#pragma unroll
    for (int j = 0; j < VEC; ++j) acc[j] += w * bfu2f(r[j]);
  }

  if constexpr (sizeof(OT) == 4) {  // float out, add bias
#pragma unroll
    for (int j = 0; j < VEC; ++j)
      ((float*)H)[(size_t)d * F + off + j] = acc[j] + bias[off + j];
  } else {  // bf16 out, no bias
#pragma unroll
    for (int j = 0; j < VEC; ++j)
      ((__hip_bfloat16*)H)[(size_t)d * F + off + j] = __float2bfloat16(acc[j]);
  }
}

// ================= BN stats over relu(H) =================
__global__ __launch_bounds__(256) void stat_kernel(const float* __restrict__ H,
                                                   float* __restrict__ stats, int Nn, int F) {
  int tid = (int)threadIdx.x;
  int c = tid & (F - 1);
  int rg = tid / F;
  int RP = 256 / F;
  float s = 0.f, sq = 0.f;
  for (int r = blockIdx.x * RP + rg; r < Nn; r += gridDim.x * RP) {
    float v = H[(size_t)r * F + c];
    v = fmaxf(v, 0.f);
    s += v;
    sq += v * v;
  }
  __shared__ float ls[256], lq[256];
  ls[tid] = s; lq[tid] = sq;
  __syncthreads();
  for (int str = 128; str >= F; str >>= 1) {
    if (tid < str) { ls[tid] += ls[tid + str]; lq[tid] += lq[tid + str]; }
    __syncthreads();
  }
  if (tid < F) {
    atomicAdd(&stats[c], ls[tid]);
    atomicAdd(&stats[256 + c], lq[tid]);
  }
}

__global__ void bnfin_kernel(const float* __restrict__ stats, const float* __restrict__ g,
                             const float* __restrict__ beta, float* __restrict__ ss,
                             int Nn, int F) {
  int c = (int)threadIdx.x;
  if (c >= F) return;
  float mean = stats[c] / (float)Nn;
  float var = stats[256 + c] / (float)Nn - mean * mean;
  float sc = g[c] * rsqrtf(var + EPS_BN);
  ss[c] = sc;
  ss[256 + c] = beta[c] - mean * sc;
}

__global__ void bnapply_kernel(const float* __restrict__ H, const float* __restrict__ ss,
                               __hip_bfloat16* __restrict__ O, size_t total4, int F) {
  size_t i = (size_t)blockIdx.x * blockDim.x + threadIdx.x;
  size_t stride = (size_t)gridDim.x * blockDim.x;
  for (; i < total4; i += stride) {
    size_t b = i * 4;
    float4 v = *(const float4*)&H[b];
    int c = (int)(b & (size_t)(F - 1));
    union { ushort4 u; __hip_bfloat16 h[4]; } pk;
    pk.h[0] = __float2bfloat16(fmaxf(v.x, 0.f) * ss[c + 0] + ss[256 + c + 0]);
    pk.h[1] = __float2bfloat16(fmaxf(v.y, 0.f) * ss[c + 1] + ss[256 + c + 1]);
    pk.h[2] = __float2bfloat16(fmaxf(v.z, 0.f) * ss[c + 2] + ss[256 + c + 2]);
    pk.h[3] = __float2bfloat16(fmaxf(v.w, 0.f) * ss[c + 3] + ss[256 + c + 3]);
    *(ushort4*)&O[b] = pk.u;
  }
}

// ================= classifier =================
__global__ __launch_bounds__(256) void cls_kernel(const __hip_bfloat16* __restrict__ H,
                                                  const float* __restrict__ Wc,
                                                  const float* __restrict__ bc,
                                                  float* __restrict__ out, int Nn) {
  int gt = blockIdx.x * blockDim.x + (int)threadIdx.x;
  int wid = gt >> 6;
  int lane = (int)threadIdx.x & 63;
  if (wid >= Nn) return;
  float v = __bfloat162float(H[(size_t)wid * 64 + lane]);
#pragma unroll
  for (int c = 0; c < 10; ++c) {
    float p = v * Wc[lane * 10 + c];
#pragma unroll
    for (int off = 32; off > 0; off >>= 1) p += __shfl_down(p, off, 64);
    if (lane == 0) out[(size_t)wid * 10 + c] = p + bc[c];
  }
}

// ================= host launch =================

extern "C" void kernel_launch(void* const* d_in, const int* in_sizes, int n_in,
                              void* d_out, int out_size, void* d_ws, size_t ws_size,
                              hipStream_t stream) {
  (void)n_in; (void)out_size; (void)ws_size;
  const float* x    = (const float*)d_in[0];
  const int*   edge = (const int*)d_in[1];
  const int E  = in_sizes[1] / 2;
  const int Nn = in_sizes[0] / 512;
  const int* e_src = edge;
  const int* e_dst = edge + E;

  const float* W[4]  = {(const float*)d_in[2],  (const float*)d_in[6],
                        (const float*)d_in[10], (const float*)d_in[14]};
  const float* bv[4] = {(const float*)d_in[3],  (const float*)d_in[7],
                        (const float*)d_in[11], (const float*)d_in[15]};
  const float* gv[4] = {(const float*)d_in[4],  (const float*)d_in[8],
                        (const float*)d_in[12], (const float*)d_in[16]};
  const float* bt[4] = {(const float*)d_in[5],  (const float*)d_in[9],
                        (const float*)d_in[13], (const float*)d_in[17]};
  const float* Wc = (const float*)d_in[18];
  const float* bc = (const float*)d_in[19];
  float* out = (float*)d_out;

  const int Kdim[4] = {512, 128, 256, 128};
  const int Fdim[4] = {128, 256, 128, 64};

  char* p = (char*)d_ws;
  auto alloc = [&](size_t bytes) -> void* {
    void* r = (void*)p;
    p += (bytes + 255) & ~(size_t)255;
    return r;
  };
  int*   cnt      = (int*)alloc((size_t)Nn * 4);
  int*   cursor   = (int*)alloc((size_t)Nn * 4);
  int*   rowstart = (int*)alloc((size_t)(Nn + 1) * 4);
  int*   bsum     = (int*)alloc(1024 * 4);
  float* dis      = (float*)alloc((size_t)Nn * 4);
  float* stats    = (float*)alloc(512 * 4);
  float* ss       = (float*)alloc(512 * 4);
  int*   csr_src  = (int*)alloc((size_t)E * 4);
  float* csr_w    = (float*)alloc((size_t)E * 4);
  __hip_bfloat16* Wt[4];
  for (int l = 0; l < 4; ++l)
    Wt[l] = (__hip_bfloat16*)alloc((size_t)Kdim[l] * Fdim[l] * 2);
  // R0: x_bf16 [Nn*512]*2B during GEMM1, then reused as fp32 H [Nn*256]*4B
  char* R0 = (char*)alloc((size_t)Nn * 512 * 2);
  __hip_bfloat16* Tb = (__hip_bfloat16*)alloc((size_t)Nn * 256 * 2);
  __hip_bfloat16* P0 = (__hip_bfloat16*)alloc((size_t)Nn * 256 * 2);
  __hip_bfloat16* P1 = (__hip_bfloat16*)alloc((size_t)Nn * 256 * 2);
  __hip_bfloat16* Xb = (__hip_bfloat16*)R0;
  float*          Hf = (float*)R0;

  hipMemsetAsync(cnt, 0, (size_t)Nn * 4, stream);
  hipMemsetAsync(cursor, 0, (size_t)Nn * 4, stream);

  int nb = (Nn + 1023) / 1024;
  count_kernel<<<(E + 255) / 256, 256, 0, stream>>>(e_dst, cnt, E);
  dis_kernel<<<(Nn + 255) / 256, 256, 0, stream>>>(cnt, dis, Nn);
  scan1_kernel<<<nb, 1024, 0, stream>>>(cnt, rowstart, bsum, Nn);
  scan2_kernel<<<1, 1024, 0, stream>>>(bsum, nb);
  scan3_kernel<<<nb, 1024, 0, stream>>>(rowstart, bsum, Nn, E);
  scatter_kernel<<<(E + 255) / 256, 256, 0, stream>>>(e_src, e_dst, rowstart, cursor,
                                                      dis, csr_src, csr_w, E);

  for (int l = 0; l < 4; ++l) {
    int kf = Kdim[l] * Fdim[l];
    wtrans_kernel<<<(kf + 255) / 256, 256, 0, stream>>>(W[l], Wt[l], Kdim[l], Fdim[l]);
  }
  convert_bf16_kernel<<<4096, 256, 0, stream>>>(x, Xb, (size_t)Nn * 512 / 4);

  int aggBlocks = (Nn * 64 + 255) / 256;

  auto bn = [&](const float* Hsrc, int l, int F, __hip_bfloat16* Obf) {
    hipMemsetAsync(stats, 0, 512 * 4, stream);
    stat_kernel<<<1024, 256, 0, stream>>>(Hsrc, stats, Nn, F);
    bnfin_kernel<<<1, 256, 0, stream>>>(stats, gv[l], bt[l], ss, Nn, F);
    size_t total4 = (size_t)Nn * F / 4;
    bnapply_kernel<<<(int)((total4 + 255) / 256), 256, 0, stream>>>(Hsrc, ss, Obf, total4, F);
  };

  // ---- L1: GEMM(Xb[512] -> Tb[128]); agg+b1 -> Hf; BN -> P0
  {
    dim3 g((Nn + 127) / 128, 1);
    mfma_gemm_kernel<128, false><<<g, 256, 0, stream>>>(Xb, Wt[0], Tb, nullptr, Nn, 512, 128);
    agg_kernel<2, float><<<aggBlocks, 256, 0, stream>>>(Tb, rowstart, csr_src, csr_w,
                                                        dis, bv[0], Hf, Nn, 128);
    bn(Hf, 0, 128, P0);
  }
  // ---- L2 (swapped, linearity): agg(P0[128]) -> Tb bf16; GEMM+b2 -> Hf[256]; BN -> P1
  {
    agg_kernel<2, __hip_bfloat16><<<aggBlocks, 256, 0, stream>>>(P0, rowstart, csr_src, csr_w,
                                                                 dis, nullptr, Tb, Nn, 128);
    dim3 g((Nn + 127) / 128, 2);
    mfma_gemm_kernel<128, true><<<g, 256, 0, stream>>>(Tb, Wt[1], Hf, bv[1], Nn, 128, 256);
    bn(Hf, 1, 256, P1);
  }
  // ---- L3: GEMM(P1[256] -> Tb[128]); agg+b3 -> Hf; BN -> P0
  {
    dim3 g((Nn + 127) / 128, 1);
    mfma_gemm_kernel<128, false><<<g, 256, 0, stream>>>(P1, Wt[2], Tb, nullptr, Nn, 256, 128);
    agg_kernel<2, float><<<aggBlocks, 256, 0, stream>>>(Tb, rowstart, csr_src, csr_w,
                                                        dis, bv[2], Hf, Nn, 128);
    bn(Hf, 2, 128, P0);
  }
  // ---- L4: GEMM(P0[128] -> Tb[64]); agg+b4 -> Hf; BN -> P1
  {
    dim3 g((Nn + 127) / 128, 1);
    mfma_gemm_kernel<64, false><<<g, 256, 0, stream>>>(P0, Wt[3], Tb, nullptr, Nn, 128, 64);
    agg_kernel<1, float><<<aggBlocks, 256, 0, stream>>>(Tb, rowstart, csr_src, csr_w,
                                                        dis, bv[3], Hf, Nn, 64);
    bn(Hf, 3, 64, P1);
  }

  int clsBlocks = (Nn * 64 + 255) / 256;
  cls_kernel<<<clsBlocks, 256, 0, stream>>>(P1, Wc, bc, out, Nn);
}

// Round 4
// 1144.013 us; speedup vs baseline: 1.9560x; 1.0882x over previous
//
#include <hip/hip_runtime.h>
#include <hip/hip_bf16.h>

#define EPS_BN 1e-5f

using frag8 = __attribute__((ext_vector_type(8))) short;   // 8 bf16 (4 VGPRs)
using f32x4 = __attribute__((ext_vector_type(4))) float;   // 4 fp32 acc

typedef const __attribute__((address_space(1))) void* gas_ptr;
typedef __attribute__((address_space(3))) void* las_ptr;

__device__ __forceinline__ void async_ld16(const void* g, void* l) {
  __builtin_amdgcn_global_load_lds((gas_ptr)g, (las_ptr)l, 16, 0, 0);
}

__device__ __forceinline__ float bfu2f(unsigned short u) {
  union { unsigned int i; float f; } c;
  c.i = (unsigned int)u << 16;
  return c.f;
}

// ================= graph preprocessing =================

// ticket-issuing degree count: rank[e] = my slot within dst bucket (coalesced write).
__global__ void count_ticket_kernel(const int* __restrict__ dst, int* __restrict__ cnt,
                                    int* __restrict__ rank, int E) {
  int e = blockIdx.x * blockDim.x + threadIdx.x;
  if (e < E) rank[e] = atomicAdd(&cnt[dst[e]], 1);
}

// hierarchical exclusive scan; also emits dis = rsqrt(deg) (deg = cnt + self-loop)
__global__ void scan1_kernel(const int* __restrict__ cnt, int* __restrict__ out,
                             int* __restrict__ bsum, float* __restrict__ dis, int n) {
  __shared__ int sdata[1024];
  int tid = threadIdx.x;
  int i = blockIdx.x * 1024 + tid;
  int v = (i < n) ? cnt[i] : 0;
  if (i < n) dis[i] = rsqrtf((float)v + 1.0f);
  sdata[tid] = v;
  __syncthreads();
  for (int off = 1; off < 1024; off <<= 1) {
    int t = (tid >= off) ? sdata[tid - off] : 0;
    __syncthreads();
    sdata[tid] += t;
    __syncthreads();
  }
  if (i < n) out[i] = sdata[tid] - v;
  if (tid == 1023) bsum[blockIdx.x] = sdata[1023];
}

__global__ void scan2_kernel(int* __restrict__ bsum, int nb) {
  __shared__ int sdata[1024];
  int tid = threadIdx.x;
  int v = (tid < nb) ? bsum[tid] : 0;
  sdata[tid] = v;
  __syncthreads();
  for (int off = 1; off < 1024; off <<= 1) {
    int t = (tid >= off) ? sdata[tid - off] : 0;
    __syncthreads();
    sdata[tid] += t;
    __syncthreads();
  }
  if (tid < nb) bsum[tid] = sdata[tid] - v;
}

__global__ void scan3_kernel(int* __restrict__ out, const int* __restrict__ bsum,
                             int n, int E) {
  int i = blockIdx.x * 1024 + threadIdx.x;
  if (i < n) out[i] += bsum[blockIdx.x];
  if (i == 0) out[n] = E;
}

// atomic-free scatter: deterministic slot = rowstart[dst] + rank.
__global__ void scatter_kernel(const int* __restrict__ src, const int* __restrict__ dst,
                               const int* __restrict__ rowstart, const int* __restrict__ rank,
                               int* __restrict__ csr_src, int E) {
  int e = blockIdx.x * blockDim.x + threadIdx.x;
  if (e < E) csr_src[rowstart[dst[e]] + rank[e]] = src[e];
}

// ================= conversions =================

__global__ void convert_bf16_kernel(const float* __restrict__ in,
                                    __hip_bfloat16* __restrict__ out, size_t n4) {
  size_t i = (size_t)blockIdx.x * blockDim.x + threadIdx.x;
  size_t stride = (size_t)gridDim.x * blockDim.x;
  for (; i < n4; i += stride) {
    float4 v = *(const float4*)&in[i * 4];
    union { ushort4 u; __hip_bfloat16 h[4]; } pk;
    pk.h[0] = __float2bfloat16(v.x);
    pk.h[1] = __float2bfloat16(v.y);
    pk.h[2] = __float2bfloat16(v.z);
    pk.h[3] = __float2bfloat16(v.w);
    *(ushort4*)&out[i * 4] = pk.u;
  }
}

// all 4 weight transposes in one launch (fixed dims)
__global__ void wtrans_all_kernel(const float* __restrict__ W1, const float* __restrict__ W2,
                                  const float* __restrict__ W3, const float* __restrict__ W4,
                                  __hip_bfloat16* __restrict__ T1, __hip_bfloat16* __restrict__ T2,
                                  __hip_bfloat16* __restrict__ T3, __hip_bfloat16* __restrict__ T4) {
  int i = blockIdx.x * blockDim.x + threadIdx.x;
  const float* W; __hip_bfloat16* T; int K, F, base;
  if (i < 65536)        { W = W1; T = T1; K = 512; F = 128; base = 0; }
  else if (i < 98304)   { W = W2; T = T2; K = 128; F = 256; base = 65536; }
  else if (i < 131072)  { W = W3; T = T3; K = 256; F = 128; base = 98304; }
  else if (i < 139264)  { W = W4; T = T4; K = 128; F = 64;  base = 131072; }
  else return;
  int j = i - base;
  int k = j / F, f = j % F;
  T[f * K + k] = __float2bfloat16(W[j]);
}

// ================= bf16 MFMA GEMM: C[Nr,F] = A[Nr,K] @ Bt[F,K]^T =================
// OMODE 1: bf16 out, scaled by rowscale[row]  (produces pre-scaled Ts for agg)
// OMODE 2: fp32 out + bias[col]               (agg-first layer L2)
template <int TN, int OMODE>
__global__ __launch_bounds__(256) void mfma_gemm_kernel(
    const __hip_bfloat16* __restrict__ A, const __hip_bfloat16* __restrict__ Bt,
    void* __restrict__ Cv, const float* __restrict__ bias,
    const float* __restrict__ rowscale, int Nr, int K, int F) {
  constexpr int WM = (TN == 128) ? 64 : 32;
  constexpr int MI = WM / 16;
  __shared__ __align__(16) __hip_bfloat16 As[128 * 32];
  __shared__ __align__(16) __hip_bfloat16 Bs[TN * 32];
  int tid = (int)threadIdx.x;
  int wid = tid >> 6, lane = tid & 63;
  int rowBase = blockIdx.x * 128;
  int colBase = blockIdx.y * TN;
  int wr, wc;
  if (TN == 128) { wr = (wid >> 1) * 64; wc = (wid & 1) * 64; }
  else           { wr = wid * 32;        wc = 0; }

  f32x4 zero = {0.f, 0.f, 0.f, 0.f};
  f32x4 acc[MI][4];
#pragma unroll
  for (int i = 0; i < MI; ++i)
#pragma unroll
    for (int j = 0; j < 4; ++j) acc[i][j] = zero;

  int lm = lane & 15;
  int k8 = (lane >> 4) * 8;

  for (int k0 = 0; k0 < K; k0 += 32) {
#pragma unroll
    for (int p = 0; p < 2; ++p) {
      int sidx = p * 256 + tid;
      int row = sidx >> 2;
      int kq = (sidx & 3) * 8;
      int gr = rowBase + row;
      if (gr >= Nr) gr = Nr - 1;
      async_ld16(A + (size_t)gr * K + k0 + kq, (char*)As + (p * 256 + wid * 64) * 16);
    }
    constexpr int BPASS = TN / 64;
#pragma unroll
    for (int p = 0; p < BPASS; ++p) {
      int sidx = p * 256 + tid;
      int col = sidx >> 2;
      int kq = (sidx & 3) * 8;
      async_ld16(Bt + (size_t)(colBase + col) * K + k0 + kq,
                 (char*)Bs + (p * 256 + wid * 64) * 16);
    }
    __syncthreads();

    frag8 af[MI], bf[4];
#pragma unroll
    for (int i = 0; i < MI; ++i)
      af[i] = *(const frag8*)&As[(wr + i * 16 + lm) * 32 + k8];
#pragma unroll
    for (int j = 0; j < 4; ++j)
      bf[j] = *(const frag8*)&Bs[(wc + j * 16 + lm) * 32 + k8];
#pragma unroll
    for (int i = 0; i < MI; ++i)
#pragma unroll
      for (int j = 0; j < 4; ++j)
        acc[i][j] = __builtin_amdgcn_mfma_f32_16x16x32_bf16(af[i], bf[j], acc[i][j], 0, 0, 0);
    __syncthreads();
  }

  // C/D layout: col=lane&15, row=(lane>>4)*4+reg  [verified m89]
  int rquad = (lane >> 4) * 4;
#pragma unroll
  for (int i = 0; i < MI; ++i) {
    int rb = rowBase + wr + i * 16 + rquad;
#pragma unroll
    for (int r = 0; r < 4; ++r) {
      int row = rb + r;
      if (row < Nr) {
        if constexpr (OMODE == 1) {
          float rs = rowscale[row];
#pragma unroll
          for (int j = 0; j < 4; ++j) {
            int col = colBase + wc + j * 16 + lm;
            ((__hip_bfloat16*)Cv)[(size_t)row * F + col] = __float2bfloat16(acc[i][j][r] * rs);
          }
        } else {
#pragma unroll
          for (int j = 0; j < 4; ++j) {
            int col = colBase + wc + j * 16 + lm;
            ((float*)Cv)[(size_t)row * F + col] = acc[i][j][r] + bias[col];
          }
        }
      }
    }
  }
}

// ================= aggregation =================
// Ts rows are pre-scaled by dis[row]. agg[d] = dis[d]*(Ts[d] + sum Ts[src]) (+bias).
// one wave per dst node; lane owns VEC contiguous bf16 features; 8-wide edge unroll.
template <int VEC, bool BF16OUT>
__global__ __launch_bounds__(256) void agg_kernel(
    const __hip_bfloat16* __restrict__ Ts, const int* __restrict__ rowstart,
    const int* __restrict__ csr_src, const float* __restrict__ dis,
    const float* __restrict__ bias, void* __restrict__ H, int Nn, int F) {
  int gt = blockIdx.x * blockDim.x + (int)threadIdx.x;
  int wid = gt >> 6;
  int lane = (int)threadIdx.x & 63;
  if (wid >= Nn) return;
  int d = wid;
  int off = lane * VEC;
  const unsigned short* Tu = (const unsigned short*)Ts;

  float acc[VEC];
  {  // self term (pre-scaled row)
    unsigned short r[VEC];
    if constexpr (VEC == 2) *(ushort2*)r = *(const ushort2*)&Tu[(size_t)d * F + off];
    else                    r[0] = Tu[(size_t)d * F + off];
#pragma unroll
    for (int j = 0; j < VEC; ++j) acc[j] = bfu2f(r[j]);
  }

  int e0 = rowstart[d], e1 = rowstart[d + 1];
  int e = e0;
  for (; e + 8 <= e1; e += 8) {
    int s[8];
#pragma unroll
    for (int q = 0; q < 8; ++q) s[q] = csr_src[e + q];
    unsigned short r[8][VEC];
#pragma unroll
    for (int q = 0; q < 8; ++q) {
      if constexpr (VEC == 2) *(ushort2*)r[q] = *(const ushort2*)&Tu[(size_t)s[q] * F + off];
      else                    r[q][0] = Tu[(size_t)s[q] * F + off];
    }
#pragma unroll
    for (int q = 0; q < 8; ++q)
#pragma unroll
      for (int j = 0; j < VEC; ++j) acc[j] += bfu2f(r[q][j]);
  }
  for (; e < e1; ++e) {
    int s = csr_src[e];
    unsigned short r[VEC];
    if constexpr (VEC == 2) *(ushort2*)r = *(const ushort2*)&Tu[(size_t)s * F + off];
    else                    r[0] = Tu[(size_t)s * F + off];
#pragma unroll
    for (int j = 0; j < VEC; ++j) acc[j] += bfu2f(r[j]);
  }

  float dd = dis[d];
  if constexpr (BF16OUT) {
#pragma unroll
    for (int j = 0; j < VEC; ++j)
      ((__hip_bfloat16*)H)[(size_t)d * F + off + j] = __float2bfloat16(acc[j] * dd);
  } else {
#pragma unroll
    for (int j = 0; j < VEC; ++j)
      ((float*)H)[(size_t)d * F + off + j] = acc[j] * dd + bias[off + j];
  }
}

// ================= BN stats over relu(H) =================
__global__ __launch_bounds__(256) void stat_kernel(const float* __restrict__ H,
                                                   float* __restrict__ stats, int Nn, int F) {
  int tid = (int)threadIdx.x;
  int c = tid & (F - 1);
  int rg = tid / F;
  int RP = 256 / F;
  float s = 0.f, sq = 0.f;
  for (int r = blockIdx.x * RP + rg; r < Nn; r += gridDim.x * RP) {
    float v = H[(size_t)r * F + c];
    v = fmaxf(v, 0.f);
    s += v;
    sq += v * v;
  }
  __shared__ float ls[256], lq[256];
  ls[tid] = s; lq[tid] = sq;
  __syncthreads();
  for (int str = 128; str >= F; str >>= 1) {
    if (tid < str) { ls[tid] += ls[tid + str]; lq[tid] += lq[tid + str]; }
    __syncthreads();
  }
  if (tid < F) {
    atomicAdd(&stats[c], ls[tid]);
    atomicAdd(&stats[256 + c], lq[tid]);
  }
}

// computes ss from stats, then zeroes stats for the next layer's stat pass.
__global__ void bnfin_kernel(float* __restrict__ stats, const float* __restrict__ g,
                             const float* __restrict__ beta, float* __restrict__ ss,
                             int Nn, int F) {
  int c = (int)threadIdx.x;
  if (c < F) {
    float mean = stats[c] / (float)Nn;
    float var = stats[256 + c] / (float)Nn - mean * mean;
    float sc = g[c] * rsqrtf(var + EPS_BN);
    ss[c] = sc;
    ss[256 + c] = beta[c] - mean * sc;
  }
  stats[c] = 0.f;
  stats[256 + c] = 0.f;
}

// relu+BN apply, fp32 -> bf16; optional rowscale (pre-scale for a following agg)
__global__ void bnapply_kernel(const float* __restrict__ H, const float* __restrict__ ss,
                               const float* __restrict__ rowscale,
                               __hip_bfloat16* __restrict__ O, size_t total4, int F, int logF) {
  size_t i = (size_t)blockIdx.x * blockDim.x + threadIdx.x;
  size_t stride = (size_t)gridDim.x * blockDim.x;
  for (; i < total4; i += stride) {
    size_t b = i * 4;
    float4 v = *(const float4*)&H[b];
    int c = (int)(b & (size_t)(F - 1));
    float rs = rowscale ? rowscale[b >> logF] : 1.0f;
    union { ushort4 u; __hip_bfloat16 h[4]; } pk;
    pk.h[0] = __float2bfloat16((fmaxf(v.x, 0.f) * ss[c + 0] + ss[256 + c + 0]) * rs);
    pk.h[1] = __float2bfloat16((fmaxf(v.y, 0.f) * ss[c + 1] + ss[256 + c + 1]) * rs);
    pk.h[2] = __float2bfloat16((fmaxf(v.z, 0.f) * ss[c + 2] + ss[256 + c + 2]) * rs);
    pk.h[3] = __float2bfloat16((fmaxf(v.w, 0.f) * ss[c + 3] + ss[256 + c + 3]) * rs);
    *(ushort4*)&O[b] = pk.u;
  }
}

// ================= classifier =================
__global__ __launch_bounds__(256) void cls_kernel(const __hip_bfloat16* __restrict__ H,
                                                  const float* __restrict__ Wc,
                                                  const float* __restrict__ bc,
                                                  float* __restrict__ out, int Nn) {
  int gt = blockIdx.x * blockDim.x + (int)threadIdx.x;
  int wid = gt >> 6;
  int lane = (int)threadIdx.x & 63;
  if (wid >= Nn) return;
  float v = __bfloat162float(H[(size_t)wid * 64 + lane]);
#pragma unroll
  for (int c = 0; c < 10; ++c) {
    float p = v * Wc[lane * 10 + c];
#pragma unroll
    for (int off = 32; off > 0; off >>= 1) p += __shfl_down(p, off, 64);
    if (lane == 0) out[(size_t)wid * 10 + c] = p + bc[c];
  }
}

// ================= host launch =================

extern "C" void kernel_launch(void* const* d_in, const int* in_sizes, int n_in,
                              void* d_out, int out_size, void* d_ws, size_t ws_size,
                              hipStream_t stream) {
  (void)n_in; (void)out_size; (void)ws_size;
  const float* x    = (const float*)d_in[0];
  const int*   edge = (const int*)d_in[1];
  const int E  = in_sizes[1] / 2;
  const int Nn = in_sizes[0] / 512;
  const int* e_src = edge;
  const int* e_dst = edge + E;

  const float* W[4]  = {(const float*)d_in[2],  (const float*)d_in[6],
                        (const float*)d_in[10], (const float*)d_in[14]};
  const float* bv[4] = {(const float*)d_in[3],  (const float*)d_in[7],
                        (const float*)d_in[11], (const float*)d_in[15]};
  const float* gv[4] = {(const float*)d_in[4],  (const float*)d_in[8],
                        (const float*)d_in[12], (const float*)d_in[16]};
  const float* bt[4] = {(const float*)d_in[5],  (const float*)d_in[9],
                        (const float*)d_in[13], (const float*)d_in[17]};
  const float* Wc = (const float*)d_in[18];
  const float* bc = (const float*)d_in[19];
  float* out = (float*)d_out;

  const int Kdim[4] = {512, 128, 256, 128};
  const int Fdim[4] = {128, 256, 128, 64};

  char* p = (char*)d_ws;
  auto alloc = [&](size_t bytes) -> void* {
    void* r = (void*)p;
    p += (bytes + 255) & ~(size_t)255;
    return r;
  };
  int*   cnt      = (int*)alloc((size_t)Nn * 4);
  int*   rowstart = (int*)alloc((size_t)(Nn + 1) * 4);
  int*   bsum     = (int*)alloc(1024 * 4);
  float* dis      = (float*)alloc((size_t)Nn * 4);
  float* stats    = (float*)alloc(512 * 4);
  float* ss       = (float*)alloc(512 * 4);
  int*   rank     = (int*)alloc((size_t)E * 4);
  int*   csr_src  = (int*)alloc((size_t)E * 4);
  __hip_bfloat16* Wt[4];
  for (int l = 0; l < 4; ++l)
    Wt[l] = (__hip_bfloat16*)alloc((size_t)Kdim[l] * Fdim[l] * 2);
  // R0: x_bf16 [Nn*512]*2B during GEMM1, then reused as fp32 H [Nn*256]*4B
  char* R0 = (char*)alloc((size_t)Nn * 512 * 2);
  __hip_bfloat16* Tb = (__hip_bfloat16*)alloc((size_t)Nn * 256 * 2);
  __hip_bfloat16* P0 = (__hip_bfloat16*)alloc((size_t)Nn * 256 * 2);
  __hip_bfloat16* P1 = (__hip_bfloat16*)alloc((size_t)Nn * 256 * 2);
  __hip_bfloat16* Xb = (__hip_bfloat16*)R0;
  float*          Hf = (float*)R0;

  hipMemsetAsync(cnt, 0, (size_t)Nn * 4, stream);
  hipMemsetAsync(stats, 0, 512 * 4, stream);

  int nb = (Nn + 1023) / 1024;
  count_ticket_kernel<<<(E + 255) / 256, 256, 0, stream>>>(e_dst, cnt, rank, E);
  scan1_kernel<<<nb, 1024, 0, stream>>>(cnt, rowstart, bsum, dis, Nn);
  scan2_kernel<<<1, 1024, 0, stream>>>(bsum, nb);
  scan3_kernel<<<nb, 1024, 0, stream>>>(rowstart, bsum, Nn, E);
  scatter_kernel<<<(E + 255) / 256, 256, 0, stream>>>(e_src, e_dst, rowstart, rank,
                                                      csr_src, E);

  wtrans_all_kernel<<<(139264 + 255) / 256, 256, 0, stream>>>(W[0], W[1], W[2], W[3],
                                                              Wt[0], Wt[1], Wt[2], Wt[3]);
  convert_bf16_kernel<<<4096, 256, 0, stream>>>(x, Xb, (size_t)Nn * 512 / 4);

  int aggBlocks = (Nn * 64 + 255) / 256;

  auto bn = [&](const float* Hsrc, int l, int F, __hip_bfloat16* Obf, const float* rsc) {
    stat_kernel<<<1024, 256, 0, stream>>>(Hsrc, stats, Nn, F);
    bnfin_kernel<<<1, 256, 0, stream>>>(stats, gv[l], bt[l], ss, Nn, F);
    size_t total4 = (size_t)Nn * F / 4;
    int logF = (F == 256) ? 8 : (F == 128 ? 7 : 6);
    bnapply_kernel<<<(int)((total4 + 255) / 256), 256, 0, stream>>>(Hsrc, ss, rsc, Obf,
                                                                    total4, F, logF);
  };

  // ---- L1: GEMM(Xb[512] -> Tb[128] * dis); agg -> Hf (+b1); BN*dis -> P0
  {
    dim3 g((Nn + 127) / 128, 1);
    mfma_gemm_kernel<128, 1><<<g, 256, 0, stream>>>(Xb, Wt[0], Tb, nullptr, dis, Nn, 512, 128);
    agg_kernel<2, false><<<aggBlocks, 256, 0, stream>>>(Tb, rowstart, csr_src, dis,
                                                        bv[0], Hf, Nn, 128);
    bn(Hf, 0, 128, P0, dis);  // pre-scale for L2's agg
  }
  // ---- L2 (swapped): agg(P0[128]) -> Tb bf16; GEMM+b2 -> Hf[256]; BN -> P1
  {
    agg_kernel<2, true><<<aggBlocks, 256, 0, stream>>>(P0, rowstart, csr_src, dis,
                                                       nullptr, Tb, Nn, 128);
    dim3 g((Nn + 127) / 128, 2);
    mfma_gemm_kernel<128, 2><<<g, 256, 0, stream>>>(Tb, Wt[1], Hf, bv[1], nullptr, Nn, 128, 256);
    bn(Hf, 1, 256, P1, nullptr);
  }
  // ---- L3: GEMM(P1[256] -> Tb[128] * dis); agg -> Hf (+b3); BN -> P0
  {
    dim3 g((Nn + 127) / 128, 1);
    mfma_gemm_kernel<128, 1><<<g, 256, 0, stream>>>(P1, Wt[2], Tb, nullptr, dis, Nn, 256, 128);
    agg_kernel<2, false><<<aggBlocks, 256, 0, stream>>>(Tb, rowstart, csr_src, dis,
                                                        bv[2], Hf, Nn, 128);
    bn(Hf, 2, 128, P0, nullptr);
  }
  // ---- L4: GEMM(P0[128] -> Tb[64] * dis); agg -> Hf (+b4); BN -> P1
  {
    dim3 g((Nn + 127) / 128, 1);
    mfma_gemm_kernel<64, 1><<<g, 256, 0, stream>>>(P0, Wt[3], Tb, nullptr, dis, Nn, 128, 64);
    agg_kernel<1, false><<<aggBlocks, 256, 0, stream>>>(Tb, rowstart, csr_src, dis,
                                                        bv[3], Hf, Nn, 64);
    bn(Hf, 3, 64, P1, nullptr);
  }

  int clsBlocks = (Nn * 64 + 255) / 256;
  cls_kernel<<<clsBlocks, 256, 0, stream>>>(P1, Wc, bc, out, Nn);
}

// Round 5
// 1044.002 us; speedup vs baseline: 2.1434x; 1.0958x over previous
//
#include <hip/hip_runtime.h>
#include <hip/hip_bf16.h>

#define EPS_BN 1e-5f

using frag8 = __attribute__((ext_vector_type(8))) short;   // 8 bf16 (4 VGPRs)
using f32x4 = __attribute__((ext_vector_type(4))) float;   // 4 fp32 acc

typedef const __attribute__((address_space(1))) void* gas_ptr;
typedef __attribute__((address_space(3))) void* las_ptr;

__device__ __forceinline__ void async_ld16(const void* g, void* l) {
  __builtin_amdgcn_global_load_lds((gas_ptr)g, (las_ptr)l, 16, 0, 0);
}

__device__ __forceinline__ float bfu2f(unsigned short u) {
  union { unsigned int i; float f; } c;
  c.i = (unsigned int)u << 16;
  return c.f;
}

// ================= graph preprocessing =================

// ticket-issuing degree count: rank[e] = my slot within dst bucket (coalesced write).
__global__ void count_ticket_kernel(const int* __restrict__ dst, int* __restrict__ cnt,
                                    int* __restrict__ rank, int E) {
  int e = blockIdx.x * blockDim.x + threadIdx.x;
  if (e < E) rank[e] = atomicAdd(&cnt[dst[e]], 1);
}

// hierarchical exclusive scan; also emits dis = rsqrt(deg) (deg = cnt + self-loop)
__global__ void scan1_kernel(const int* __restrict__ cnt, int* __restrict__ out,
                             int* __restrict__ bsum, float* __restrict__ dis, int n) {
  __shared__ int sdata[1024];
  int tid = threadIdx.x;
  int i = blockIdx.x * 1024 + tid;
  int v = (i < n) ? cnt[i] : 0;
  if (i < n) dis[i] = rsqrtf((float)v + 1.0f);
  sdata[tid] = v;
  __syncthreads();
  for (int off = 1; off < 1024; off <<= 1) {
    int t = (tid >= off) ? sdata[tid - off] : 0;
    __syncthreads();
    sdata[tid] += t;
    __syncthreads();
  }
  if (i < n) out[i] = sdata[tid] - v;
  if (tid == 1023) bsum[blockIdx.x] = sdata[1023];
}

__global__ void scan2_kernel(int* __restrict__ bsum, int nb) {
  __shared__ int sdata[1024];
  int tid = threadIdx.x;
  int v = (tid < nb) ? bsum[tid] : 0;
  sdata[tid] = v;
  __syncthreads();
  for (int off = 1; off < 1024; off <<= 1) {
    int t = (tid >= off) ? sdata[tid - off] : 0;
    __syncthreads();
    sdata[tid] += t;
    __syncthreads();
  }
  if (tid < nb) bsum[tid] = sdata[tid] - v;
}

__global__ void scan3_kernel(int* __restrict__ out, const int* __restrict__ bsum,
                             int n, int E) {
  int i = blockIdx.x * 1024 + threadIdx.x;
  if (i < n) out[i] += bsum[blockIdx.x];
  if (i == 0) out[n] = E;
}

// atomic-free scatter: deterministic slot = rowstart[dst] + rank.
__global__ void scatter_kernel(const int* __restrict__ src, const int* __restrict__ dst,
                               const int* __restrict__ rowstart, const int* __restrict__ rank,
                               int* __restrict__ csr_src, int E) {
  int e = blockIdx.x * blockDim.x + threadIdx.x;
  if (e < E) csr_src[rowstart[dst[e]] + rank[e]] = src[e];
}

// ================= conversions =================

__global__ void convert_bf16_kernel(const float* __restrict__ in,
                                    __hip_bfloat16* __restrict__ out, size_t n4) {
  size_t i = (size_t)blockIdx.x * blockDim.x + threadIdx.x;
  size_t stride = (size_t)gridDim.x * blockDim.x;
  for (; i < n4; i += stride) {
    float4 v = *(const float4*)&in[i * 4];
    union { ushort4 u; __hip_bfloat16 h[4]; } pk;
    pk.h[0] = __float2bfloat16(v.x);
    pk.h[1] = __float2bfloat16(v.y);
    pk.h[2] = __float2bfloat16(v.z);
    pk.h[3] = __float2bfloat16(v.w);
    *(ushort4*)&out[i * 4] = pk.u;
  }
}

// all 4 weight transposes in one launch (fixed dims)
__global__ void wtrans_all_kernel(const float* __restrict__ W1, const float* __restrict__ W2,
                                  const float* __restrict__ W3, const float* __restrict__ W4,
                                  __hip_bfloat16* __restrict__ T1, __hip_bfloat16* __restrict__ T2,
                                  __hip_bfloat16* __restrict__ T3, __hip_bfloat16* __restrict__ T4) {
  int i = blockIdx.x * blockDim.x + threadIdx.x;
  const float* W; __hip_bfloat16* T; int K, F, base;
  if (i < 65536)        { W = W1; T = T1; K = 512; F = 128; base = 0; }
  else if (i < 98304)   { W = W2; T = T2; K = 128; F = 256; base = 65536; }
  else if (i < 131072)  { W = W3; T = T3; K = 256; F = 128; base = 98304; }
  else if (i < 139264)  { W = W4; T = T4; K = 128; F = 64;  base = 131072; }
  else return;
  int j = i - base;
  int k = j / F, f = j % F;
  T[f * K + k] = __float2bfloat16(W[j]);
}

// ================= bf16 MFMA GEMM: C[Nr,F] = A[Nr,K] @ Bt[F,K]^T =================
// OMODE 1: bf16 out, scaled by rowscale[row]   (pre-scaled Ts for agg)
// OMODE 2: fp32 out + bias[col], fused BN-stats over relu(out) (agg-first layer L2)
template <int TN, int OMODE>
__global__ __launch_bounds__(256) void mfma_gemm_kernel(
    const __hip_bfloat16* __restrict__ A, const __hip_bfloat16* __restrict__ Bt,
    void* __restrict__ Cv, const float* __restrict__ bias,
    const float* __restrict__ rowscale, float* __restrict__ stats,
    int Nr, int K, int F) {
  constexpr int WM = (TN == 128) ? 64 : 32;
  constexpr int MI = WM / 16;
  __shared__ __align__(16) __hip_bfloat16 As[128 * 32];
  __shared__ __align__(16) __hip_bfloat16 Bs[TN * 32];
  __shared__ float sacc[128], sqc[128];
  int tid = (int)threadIdx.x;
  int wid = tid >> 6, lane = tid & 63;
  int rowBase = blockIdx.x * 128;
  int colBase = blockIdx.y * TN;
  int wr, wc;
  if (TN == 128) { wr = (wid >> 1) * 64; wc = (wid & 1) * 64; }
  else           { wr = wid * 32;        wc = 0; }

  f32x4 zero = {0.f, 0.f, 0.f, 0.f};
  f32x4 acc[MI][4];
#pragma unroll
  for (int i = 0; i < MI; ++i)
#pragma unroll
    for (int j = 0; j < 4; ++j) acc[i][j] = zero;

  int lm = lane & 15;
  int k8 = (lane >> 4) * 8;

  if constexpr (OMODE == 2) {
    if (tid < 128) { sacc[tid] = 0.f; sqc[tid] = 0.f; }
  }

  for (int k0 = 0; k0 < K; k0 += 32) {
#pragma unroll
    for (int p = 0; p < 2; ++p) {
      int sidx = p * 256 + tid;
      int row = sidx >> 2;
      int kq = (sidx & 3) * 8;
      int gr = rowBase + row;
      if (gr >= Nr) gr = Nr - 1;
      async_ld16(A + (size_t)gr * K + k0 + kq, (char*)As + (p * 256 + wid * 64) * 16);
    }
    constexpr int BPASS = TN / 64;
#pragma unroll
    for (int p = 0; p < BPASS; ++p) {
      int sidx = p * 256 + tid;
      int col = sidx >> 2;
      int kq = (sidx & 3) * 8;
      async_ld16(Bt + (size_t)(colBase + col) * K + k0 + kq,
                 (char*)Bs + (p * 256 + wid * 64) * 16);
    }
    __syncthreads();

    frag8 af[MI], bf[4];
#pragma unroll
    for (int i = 0; i < MI; ++i)
      af[i] = *(const frag8*)&As[(wr + i * 16 + lm) * 32 + k8];
#pragma unroll
    for (int j = 0; j < 4; ++j)
      bf[j] = *(const frag8*)&Bs[(wc + j * 16 + lm) * 32 + k8];
#pragma unroll
    for (int i = 0; i < MI; ++i)
#pragma unroll
      for (int j = 0; j < 4; ++j)
        acc[i][j] = __builtin_amdgcn_mfma_f32_16x16x32_bf16(af[i], bf[j], acc[i][j], 0, 0, 0);
    __syncthreads();
  }

  // C/D layout: col=lane&15, row=(lane>>4)*4+reg  [verified m89]
  int rquad = (lane >> 4) * 4;
  float s[4] = {0.f, 0.f, 0.f, 0.f}, q[4] = {0.f, 0.f, 0.f, 0.f};
#pragma unroll
  for (int i = 0; i < MI; ++i) {
    int rb = rowBase + wr + i * 16 + rquad;
#pragma unroll
    for (int r = 0; r < 4; ++r) {
      int row = rb + r;
      if (row < Nr) {
        if constexpr (OMODE == 1) {
          float rs = rowscale[row];
#pragma unroll
          for (int j = 0; j < 4; ++j) {
            int col = colBase + wc + j * 16 + lm;
            ((__hip_bfloat16*)Cv)[(size_t)row * F + col] = __float2bfloat16(acc[i][j][r] * rs);
          }
        } else {
#pragma unroll
          for (int j = 0; j < 4; ++j) {
            int col = colBase + wc + j * 16 + lm;
            float v = acc[i][j][r] + bias[col];
            ((float*)Cv)[(size_t)row * F + col] = v;
            float rl = fmaxf(v, 0.f);
            s[j] += rl;
            q[j] += rl * rl;
          }
        }
      }
    }
  }

  if constexpr (OMODE == 2) {
    // reduce over the 4 row-quads (lanes lm, lm+16, lm+32, lm+48 share cols)
#pragma unroll
    for (int j = 0; j < 4; ++j) {
      s[j] += __shfl_xor(s[j], 16, 64); s[j] += __shfl_xor(s[j], 32, 64);
      q[j] += __shfl_xor(q[j], 16, 64); q[j] += __shfl_xor(q[j], 32, 64);
    }
    if (lane < 16) {
#pragma unroll
      for (int j = 0; j < 4; ++j) {
        atomicAdd(&sacc[wc + j * 16 + lane], s[j]);
        atomicAdd(&sqc[wc + j * 16 + lane], q[j]);
      }
    }
    __syncthreads();
    if (tid < 128) {
      atomicAdd(&stats[colBase + tid], sacc[tid]);
      atomicAdd(&stats[256 + colBase + tid], sqc[tid]);
    }
  }
}

// ================= aggregation (persistent grid-stride, fused BN-stats) =========
// Ts rows pre-scaled by dis[row]. agg[d] = dis[d]*(Ts[d] + sum Ts[src]) (+bias).
// OMODE 0: bf16 out (L2 pre-agg).  OMODE 1: fp32 out + bias + fused relu-stats.
// 8-deep branchless gather batches (clamped index + select) for full MLP.
template <int VEC, int OMODE>
__global__ __launch_bounds__(256) void agg_kernel(
    const __hip_bfloat16* __restrict__ Ts, const int* __restrict__ rowstart,
    const int* __restrict__ csr_src, const float* __restrict__ dis,
    const float* __restrict__ bias, void* __restrict__ H,
    float* __restrict__ stats, int Nn, int F) {
  __shared__ float lsum[512], lqs[512];
  int tid = (int)threadIdx.x;
  int wid4 = tid >> 6;
  int lane = tid & 63;
  int off = lane * VEC;
  const unsigned short* Tu = (const unsigned short*)Ts;

  float bj[VEC];
  float s[VEC], q[VEC];
#pragma unroll
  for (int j = 0; j < VEC; ++j) {
    bj[j] = (OMODE == 1) ? bias[off + j] : 0.f;
    s[j] = 0.f; q[j] = 0.f;
  }

  for (int d = blockIdx.x * 4 + wid4; d < Nn; d += gridDim.x * 4) {
    float acc[VEC];
    {  // self term (pre-scaled row)
      unsigned short r[VEC];
      if constexpr (VEC == 2) *(ushort2*)r = *(const ushort2*)&Tu[(size_t)d * F + off];
      else                    r[0] = Tu[(size_t)d * F + off];
#pragma unroll
      for (int j = 0; j < VEC; ++j) acc[j] = bfu2f(r[j]);
    }

    int e0 = rowstart[d], e1 = rowstart[d + 1];
    for (int e = e0; e < e1; e += 8) {
      int idx[8];
      bool val[8];
#pragma unroll
      for (int p = 0; p < 8; ++p) {
        int ee = e + p;
        val[p] = ee < e1;
        idx[p] = csr_src[val[p] ? ee : e1 - 1];
      }
      unsigned short r[8][VEC];
#pragma unroll
      for (int p = 0; p < 8; ++p) {
        if constexpr (VEC == 2) *(ushort2*)r[p] = *(const ushort2*)&Tu[(size_t)idx[p] * F + off];
        else                    r[p][0] = Tu[(size_t)idx[p] * F + off];
      }
#pragma unroll
      for (int p = 0; p < 8; ++p)
#pragma unroll
        for (int j = 0; j < VEC; ++j) acc[j] += val[p] ? bfu2f(r[p][j]) : 0.f;
    }

    float dd = dis[d];
    if constexpr (OMODE == 0) {
      union { ushort2 u; __hip_bfloat16 h[2]; } pk;
      if constexpr (VEC == 2) {
        pk.h[0] = __float2bfloat16(acc[0] * dd);
        pk.h[1] = __float2bfloat16(acc[1] * dd);
        *(ushort2*)&((__hip_bfloat16*)H)[(size_t)d * F + off] = pk.u;
      } else {
        ((__hip_bfloat16*)H)[(size_t)d * F + off] = __float2bfloat16(acc[0] * dd);
      }
    } else {
      float v[VEC];
#pragma unroll
      for (int j = 0; j < VEC; ++j) {
        v[j] = acc[j] * dd + bj[j];
        float rl = fmaxf(v[j], 0.f);
        s[j] += rl;
        q[j] += rl * rl;
      }
      if constexpr (VEC == 2) {
        *(float2*)&((float*)H)[(size_t)d * F + off] = make_float2(v[0], v[1]);
      } else {
        ((float*)H)[(size_t)d * F + off] = v[0];
      }
    }
  }

  if constexpr (OMODE == 1) {
    // block-level reduce across the 4 waves (same cols), then 2F atomics
#pragma unroll
    for (int j = 0; j < VEC; ++j) {
      lsum[(lane * VEC + j) * 4 + wid4] = s[j];
      lqs[(lane * VEC + j) * 4 + wid4] = q[j];
    }
    __syncthreads();
    int nc = 64 * VEC;  // == F
    for (int c = tid; c < nc; c += 256) {
      float a = lsum[c * 4 + 0] + lsum[c * 4 + 1] + lsum[c * 4 + 2] + lsum[c * 4 + 3];
      float b = lqs[c * 4 + 0] + lqs[c * 4 + 1] + lqs[c * 4 + 2] + lqs[c * 4 + 3];
      atomicAdd(&stats[c], a);
      atomicAdd(&stats[256 + c], b);
    }
  }
}

// computes ss from stats, then zeroes stats for the next layer's accumulation.
__global__ void bnfin_kernel(float* __restrict__ stats, const float* __restrict__ g,
                             const float* __restrict__ beta, float* __restrict__ ss,
                             int Nn, int F) {
  int c = (int)threadIdx.x;
  if (c < F) {
    float mean = stats[c] / (float)Nn;
    float var = stats[256 + c] / (float)Nn - mean * mean;
    float sc = g[c] * rsqrtf(var + EPS_BN);
    ss[c] = sc;
    ss[256 + c] = beta[c] - mean * sc;
  }
  stats[c] = 0.f;
  stats[256 + c] = 0.f;
}

// relu+BN apply, fp32 -> bf16; optional rowscale (pre-scale for a following agg)
__global__ void bnapply_kernel(const float* __restrict__ H, const float* __restrict__ ss,
                               const float* __restrict__ rowscale,
                               __hip_bfloat16* __restrict__ O, size_t total4, int F, int logF) {
  size_t i = (size_t)blockIdx.x * blockDim.x + threadIdx.x;
  size_t stride = (size_t)gridDim.x * blockDim.x;
  for (; i < total4; i += stride) {
    size_t b = i * 4;
    float4 v = *(const float4*)&H[b];
    int c = (int)(b & (size_t)(F - 1));
    float rs = rowscale ? rowscale[b >> logF] : 1.0f;
    union { ushort4 u; __hip_bfloat16 h[4]; } pk;
    pk.h[0] = __float2bfloat16((fmaxf(v.x, 0.f) * ss[c + 0] + ss[256 + c + 0]) * rs);
    pk.h[1] = __float2bfloat16((fmaxf(v.y, 0.f) * ss[c + 1] + ss[256 + c + 1]) * rs);
    pk.h[2] = __float2bfloat16((fmaxf(v.z, 0.f) * ss[c + 2] + ss[256 + c + 2]) * rs);
    pk.h[3] = __float2bfloat16((fmaxf(v.w, 0.f) * ss[c + 3] + ss[256 + c + 3]) * rs);
    *(ushort4*)&O[b] = pk.u;
  }
}

// ================= fused L4 BN-apply + classifier =================
// one wave per row: h = BN(relu(Hf[row,:64])) in fp32; out[row,c] = h . Wc[:,c] + bc
__global__ __launch_bounds__(256) void bnapply_cls_kernel(
    const float* __restrict__ Hf, const float* __restrict__ ss,
    const float* __restrict__ Wc, const float* __restrict__ bc,
    float* __restrict__ out, int Nn) {
  int gt = blockIdx.x * blockDim.x + (int)threadIdx.x;
  int wid = gt >> 6;
  int lane = (int)threadIdx.x & 63;
  if (wid >= Nn) return;
  float v = Hf[(size_t)wid * 64 + lane];
  float h = fmaxf(v, 0.f) * ss[lane] + ss[256 + lane];
#pragma unroll
  for (int c = 0; c < 10; ++c) {
    float p = h * Wc[lane * 10 + c];
#pragma unroll
    for (int off = 32; off > 0; off >>= 1) p += __shfl_down(p, off, 64);
    if (lane == 0) out[(size_t)wid * 10 + c] = p + bc[c];
  }
}

// ================= host launch =================

extern "C" void kernel_launch(void* const* d_in, const int* in_sizes, int n_in,
                              void* d_out, int out_size, void* d_ws, size_t ws_size,
                              hipStream_t stream) {
  (void)n_in; (void)out_size; (void)ws_size;
  const float* x    = (const float*)d_in[0];
  const int*   edge = (const int*)d_in[1];
  const int E  = in_sizes[1] / 2;
  const int Nn = in_sizes[0] / 512;
  const int* e_src = edge;
  const int* e_dst = edge + E;

  const float* W[4]  = {(const float*)d_in[2],  (const float*)d_in[6],
                        (const float*)d_in[10], (const float*)d_in[14]};
  const float* bv[4] = {(const float*)d_in[3],  (const float*)d_in[7],
                        (const float*)d_in[11], (const float*)d_in[15]};
  const float* gv[4] = {(const float*)d_in[4],  (const float*)d_in[8],
                        (const float*)d_in[12], (const float*)d_in[16]};
  const float* bt[4] = {(const float*)d_in[5],  (const float*)d_in[9],
                        (const float*)d_in[13], (const float*)d_in[17]};
  const float* Wc = (const float*)d_in[18];
  const float* bc = (const float*)d_in[19];
  float* out = (float*)d_out;

  const int Kdim[4] = {512, 128, 256, 128};
  const int Fdim[4] = {128, 256, 128, 64};

  char* p = (char*)d_ws;
  auto alloc = [&](size_t bytes) -> void* {
    void* r = (void*)p;
    p += (bytes + 255) & ~(size_t)255;
    return r;
  };
  int*   cnt      = (int*)alloc((size_t)Nn * 4);
  int*   rowstart = (int*)alloc((size_t)(Nn + 1) * 4);
  int*   bsum     = (int*)alloc(1024 * 4);
  float* dis      = (float*)alloc((size_t)Nn * 4);
  float* stats    = (float*)alloc(512 * 4);
  float* ss       = (float*)alloc(512 * 4);
  int*   rank     = (int*)alloc((size_t)E * 4);
  int*   csr_src  = (int*)alloc((size_t)E * 4);
  __hip_bfloat16* Wt[4];
  for (int l = 0; l < 4; ++l)
    Wt[l] = (__hip_bfloat16*)alloc((size_t)Kdim[l] * Fdim[l] * 2);
  // R0: x_bf16 [Nn*512]*2B during GEMM1, then reused as fp32 H [Nn*256]*4B
  char* R0 = (char*)alloc((size_t)Nn * 512 * 2);
  __hip_bfloat16* Tb = (__hip_bfloat16*)alloc((size_t)Nn * 256 * 2);
  __hip_bfloat16* P0 = (__hip_bfloat16*)alloc((size_t)Nn * 256 * 2);
  __hip_bfloat16* P1 = (__hip_bfloat16*)alloc((size_t)Nn * 256 * 2);
  __hip_bfloat16* Xb = (__hip_bfloat16*)R0;
  float*          Hf = (float*)R0;

  hipMemsetAsync(cnt, 0, (size_t)Nn * 4, stream);
  hipMemsetAsync(stats, 0, 512 * 4, stream);

  int nb = (Nn + 1023) / 1024;
  count_ticket_kernel<<<(E + 255) / 256, 256, 0, stream>>>(e_dst, cnt, rank, E);
  scan1_kernel<<<nb, 1024, 0, stream>>>(cnt, rowstart, bsum, dis, Nn);
  scan2_kernel<<<1, 1024, 0, stream>>>(bsum, nb);
  scan3_kernel<<<nb, 1024, 0, stream>>>(rowstart, bsum, Nn, E);
  scatter_kernel<<<(E + 255) / 256, 256, 0, stream>>>(e_src, e_dst, rowstart, rank,
                                                      csr_src, E);

  wtrans_all_kernel<<<(139264 + 255) / 256, 256, 0, stream>>>(W[0], W[1], W[2], W[3],
                                                              Wt[0], Wt[1], Wt[2], Wt[3]);
  convert_bf16_kernel<<<4096, 256, 0, stream>>>(x, Xb, (size_t)Nn * 512 / 4);

  const int AGG_BLOCKS = 1536;  // 4 nodes/block-pass, 24 waves/CU

  auto bnapply = [&](int l, int F, __hip_bfloat16* Obf, const float* rsc) {
    bnfin_kernel<<<1, 256, 0, stream>>>(stats, gv[l], bt[l], ss, Nn, F);
    size_t total4 = (size_t)Nn * F / 4;
    int logF = (F == 256) ? 8 : (F == 128 ? 7 : 6);
    bnapply_kernel<<<(int)((total4 + 255) / 256), 256, 0, stream>>>(Hf, ss, rsc, Obf,
                                                                    total4, F, logF);
  };

  // ---- L1: GEMM(Xb[512] -> Tb[128] * dis); agg+b1+stats -> Hf; BN*dis -> P0
  {
    dim3 g((Nn + 127) / 128, 1);
    mfma_gemm_kernel<128, 1><<<g, 256, 0, stream>>>(Xb, Wt[0], Tb, nullptr, dis, nullptr,
                                                    Nn, 512, 128);
    agg_kernel<2, 1><<<AGG_BLOCKS, 256, 0, stream>>>(Tb, rowstart, csr_src, dis,
                                                     bv[0], Hf, stats, Nn, 128);
    bnapply(0, 128, P0, dis);  // pre-scale for L2's agg
  }
  // ---- L2 (swapped): agg(P0[128]) -> Tb bf16; GEMM+b2+stats -> Hf[256]; BN -> P1
  {
    agg_kernel<2, 0><<<AGG_BLOCKS, 256, 0, stream>>>(P0, rowstart, csr_src, dis,
                                                     nullptr, Tb, nullptr, Nn, 128);
    dim3 g((Nn + 127) / 128, 2);
    mfma_gemm_kernel<128, 2><<<g, 256, 0, stream>>>(Tb, Wt[1], Hf, bv[1], nullptr, stats,
                                                    Nn, 128, 256);
    bnapply(1, 256, P1, nullptr);
  }
  // ---- L3: GEMM(P1[256] -> Tb[128] * dis); agg+b3+stats -> Hf; BN -> P0
  {
    dim3 g((Nn + 127) / 128, 1);
    mfma_gemm_kernel<128, 1><<<g, 256, 0, stream>>>(P1, Wt[2], Tb, nullptr, dis, nullptr,
                                                    Nn, 256, 128);
    agg_kernel<2, 1><<<AGG_BLOCKS, 256, 0, stream>>>(Tb, rowstart, csr_src, dis,
                                                     bv[2], Hf, stats, Nn, 128);
    bnapply(2, 128, P0, nullptr);
  }
  // ---- L4: GEMM(P0[128] -> Tb[64] * dis); agg+b4+stats -> Hf; fused BN+cls -> out
  {
    dim3 g((Nn + 127) / 128, 1);
    mfma_gemm_kernel<64, 1><<<g, 256, 0, stream>>>(P0, Wt[3], Tb, nullptr, dis, nullptr,
                                                   Nn, 128, 64);
    agg_kernel<1, 1><<<AGG_BLOCKS, 256, 0, stream>>>(Tb, rowstart, csr_src, dis,
                                                     bv[3], Hf, stats, Nn, 64);
    bnfin_kernel<<<1, 256, 0, stream>>>(stats, gv[3], bt[3], ss, Nn, 64);
    int clsBlocks = (Nn * 64 + 255) / 256;
    bnapply_cls_kernel<<<clsBlocks, 256, 0, stream>>>(Hf, ss, Wc, bc, out, Nn);
  }
}

// Round 6
// 1040.413 us; speedup vs baseline: 2.1508x; 1.0034x over previous
//
#include <hip/hip_runtime.h>
#include <hip/hip_bf16.h>

#define EPS_BN 1e-5f

using frag8 = __attribute__((ext_vector_type(8))) short;   // 8 bf16 (4 VGPRs)
using f32x4 = __attribute__((ext_vector_type(4))) float;   // 4 fp32 acc

typedef const __attribute__((address_space(1))) void* gas_ptr;
typedef __attribute__((address_space(3))) void* las_ptr;

__device__ __forceinline__ void async_ld16(const void* g, void* l) {
  __builtin_amdgcn_global_load_lds((gas_ptr)g, (las_ptr)l, 16, 0, 0);
}

__device__ __forceinline__ float bfu2f(unsigned short u) {
  union { unsigned int i; float f; } c;
  c.i = (unsigned int)u << 16;
  return c.f;
}

// ================= fat prep kernel: count_ticket || convert_bf16 || wtrans ==========
// Block roles by blockIdx range; no cross-block deps. Overlaps the latency-bound
// ticket atomics with the BW-bound fp32->bf16 convert and weight transposes.
__global__ __launch_bounds__(256) void prep_fat_kernel(
    const int* __restrict__ e_dst, int* __restrict__ cnt, int* __restrict__ rank, int E,
    int CB,
    const float* __restrict__ x, __hip_bfloat16* __restrict__ Xb, size_t n4, int VB,
    const float* __restrict__ W1, const float* __restrict__ W2,
    const float* __restrict__ W3, const float* __restrict__ W4,
    __hip_bfloat16* __restrict__ T1, __hip_bfloat16* __restrict__ T2,
    __hip_bfloat16* __restrict__ T3, __hip_bfloat16* __restrict__ T4) {
  int b = (int)blockIdx.x;
  int tid = (int)threadIdx.x;
  if (b < CB) {
    // ticket-issuing degree count: rank[e] = slot within dst bucket
    int e = b * 256 + tid;
    if (e < E) rank[e] = atomicAdd(&cnt[e_dst[e]], 1);
  } else if (b < CB + VB) {
    size_t i = (size_t)(b - CB) * 256 + tid;
    size_t stride = (size_t)VB * 256;
    for (; i < n4; i += stride) {
      float4 v = *(const float4*)&x[i * 4];
      union { ushort4 u; __hip_bfloat16 h[4]; } pk;
      pk.h[0] = __float2bfloat16(v.x);
      pk.h[1] = __float2bfloat16(v.y);
      pk.h[2] = __float2bfloat16(v.z);
      pk.h[3] = __float2bfloat16(v.w);
      *(ushort4*)&Xb[i * 4] = pk.u;
    }
  } else {
    int i = (b - CB - VB) * 256 + tid;
    const float* W; __hip_bfloat16* T; int F, K, base;
    if (i < 65536)        { W = W1; T = T1; K = 512; F = 128; base = 0; }
    else if (i < 98304)   { W = W2; T = T2; K = 128; F = 256; base = 65536; }
    else if (i < 131072)  { W = W3; T = T3; K = 256; F = 128; base = 98304; }
    else if (i < 139264)  { W = W4; T = T4; K = 128; F = 64;  base = 131072; }
    else return;
    int j = i - base;
    int k = j / F, f = j % F;
    T[f * K + k] = __float2bfloat16(W[j]);
  }
}

// ================= hierarchical exclusive scan (+ dis = rsqrt(deg)) =================
__global__ void scan1_kernel(const int* __restrict__ cnt, int* __restrict__ out,
                             int* __restrict__ bsum, float* __restrict__ dis, int n) {
  __shared__ int sdata[1024];
  int tid = threadIdx.x;
  int i = blockIdx.x * 1024 + tid;
  int v = (i < n) ? cnt[i] : 0;
  if (i < n) dis[i] = rsqrtf((float)v + 1.0f);
  sdata[tid] = v;
  __syncthreads();
  for (int off = 1; off < 1024; off <<= 1) {
    int t = (tid >= off) ? sdata[tid - off] : 0;
    __syncthreads();
    sdata[tid] += t;
    __syncthreads();
  }
  if (i < n) out[i] = sdata[tid] - v;
  if (tid == 1023) bsum[blockIdx.x] = sdata[1023];
}

__global__ void scan2_kernel(int* __restrict__ bsum, int nb) {
  __shared__ int sdata[1024];
  int tid = threadIdx.x;
  int v = (tid < nb) ? bsum[tid] : 0;
  sdata[tid] = v;
  __syncthreads();
  for (int off = 1; off < 1024; off <<= 1) {
    int t = (tid >= off) ? sdata[tid - off] : 0;
    __syncthreads();
    sdata[tid] += t;
    __syncthreads();
  }
  if (tid < nb) bsum[tid] = sdata[tid] - v;
}

__global__ void scan3_kernel(int* __restrict__ out, const int* __restrict__ bsum,
                             int n, int E) {
  int i = blockIdx.x * 1024 + threadIdx.x;
  if (i < n) out[i] += bsum[blockIdx.x];
  if (i == 0) out[n] = E;
}

// ================= bf16 MFMA GEMM body: C[Nr,F] = A[Nr,K] @ Bt[F,K]^T ===========
// OMODE 1: bf16 out, scaled by rowscale[row]   (pre-scaled Ts for agg)
// OMODE 2: fp32 out + bias[col], fused BN-stats over relu(out) (agg-first layer L2)
template <int TN, int OMODE>
__device__ __forceinline__ void gemm_body(
    const __hip_bfloat16* __restrict__ A, const __hip_bfloat16* __restrict__ Bt,
    void* __restrict__ Cv, const float* __restrict__ bias,
    const float* __restrict__ rowscale, float* __restrict__ stats,
    int Nr, int K, int F, int bx, int by) {
  constexpr int WM = (TN == 128) ? 64 : 32;
  constexpr int MI = WM / 16;
  __shared__ __align__(16) __hip_bfloat16 As[128 * 32];
  __shared__ __align__(16) __hip_bfloat16 Bs[TN * 32];
  __shared__ float sacc[128], sqc[128];
  int tid = (int)threadIdx.x;
  int wid = tid >> 6, lane = tid & 63;
  int rowBase = bx * 128;
  int colBase = by * TN;
  int wr, wc;
  if (TN == 128) { wr = (wid >> 1) * 64; wc = (wid & 1) * 64; }
  else           { wr = wid * 32;        wc = 0; }

  f32x4 zero = {0.f, 0.f, 0.f, 0.f};
  f32x4 acc[MI][4];
#pragma unroll
  for (int i = 0; i < MI; ++i)
#pragma unroll
    for (int j = 0; j < 4; ++j) acc[i][j] = zero;

  int lm = lane & 15;
  int k8 = (lane >> 4) * 8;

  if constexpr (OMODE == 2) {
    if (tid < 128) { sacc[tid] = 0.f; sqc[tid] = 0.f; }
  }

  for (int k0 = 0; k0 < K; k0 += 32) {
#pragma unroll
    for (int p = 0; p < 2; ++p) {
      int sidx = p * 256 + tid;
      int row = sidx >> 2;
      int kq = (sidx & 3) * 8;
      int gr = rowBase + row;
      if (gr >= Nr) gr = Nr - 1;
      async_ld16(A + (size_t)gr * K + k0 + kq, (char*)As + (p * 256 + wid * 64) * 16);
    }
    constexpr int BPASS = TN / 64;
#pragma unroll
    for (int p = 0; p < BPASS; ++p) {
      int sidx = p * 256 + tid;
      int col = sidx >> 2;
      int kq = (sidx & 3) * 8;
      async_ld16(Bt + (size_t)(colBase + col) * K + k0 + kq,
                 (char*)Bs + (p * 256 + wid * 64) * 16);
    }
    __syncthreads();

    frag8 af[MI], bf[4];
#pragma unroll
    for (int i = 0; i < MI; ++i)
      af[i] = *(const frag8*)&As[(wr + i * 16 + lm) * 32 + k8];
#pragma unroll
    for (int j = 0; j < 4; ++j)
      bf[j] = *(const frag8*)&Bs[(wc + j * 16 + lm) * 32 + k8];
#pragma unroll
    for (int i = 0; i < MI; ++i)
#pragma unroll
      for (int j = 0; j < 4; ++j)
        acc[i][j] = __builtin_amdgcn_mfma_f32_16x16x32_bf16(af[i], bf[j], acc[i][j], 0, 0, 0);
    __syncthreads();
  }

  // C/D layout: col=lane&15, row=(lane>>4)*4+reg  [verified m89]
  int rquad = (lane >> 4) * 4;
  float s[4] = {0.f, 0.f, 0.f, 0.f}, q[4] = {0.f, 0.f, 0.f, 0.f};
#pragma unroll
  for (int i = 0; i < MI; ++i) {
    int rb = rowBase + wr + i * 16 + rquad;
#pragma unroll
    for (int r = 0; r < 4; ++r) {
      int row = rb + r;
      if (row < Nr) {
        if constexpr (OMODE == 1) {
          float rs = rowscale[row];
#pragma unroll
          for (int j = 0; j < 4; ++j) {
            int col = colBase + wc + j * 16 + lm;
            ((__hip_bfloat16*)Cv)[(size_t)row * F + col] = __float2bfloat16(acc[i][j][r] * rs);
          }
        } else {
#pragma unroll
          for (int j = 0; j < 4; ++j) {
            int col = colBase + wc + j * 16 + lm;
            float v = acc[i][j][r] + bias[col];
            ((float*)Cv)[(size_t)row * F + col] = v;
            float rl = fmaxf(v, 0.f);
            s[j] += rl;
            q[j] += rl * rl;
          }
        }
      }
    }
  }

  if constexpr (OMODE == 2) {
#pragma unroll
    for (int j = 0; j < 4; ++j) {
      s[j] += __shfl_xor(s[j], 16, 64); s[j] += __shfl_xor(s[j], 32, 64);
      q[j] += __shfl_xor(q[j], 16, 64); q[j] += __shfl_xor(q[j], 32, 64);
    }
    if (lane < 16) {
#pragma unroll
      for (int j = 0; j < 4; ++j) {
        atomicAdd(&sacc[wc + j * 16 + lane], s[j]);
        atomicAdd(&sqc[wc + j * 16 + lane], q[j]);
      }
    }
    __syncthreads();
    if (tid < 128) {
      atomicAdd(&stats[colBase + tid], sacc[tid]);
      atomicAdd(&stats[256 + colBase + tid], sqc[tid]);
    }
  }
}

template <int TN, int OMODE>
__global__ __launch_bounds__(256) void mfma_gemm_kernel(
    const __hip_bfloat16* __restrict__ A, const __hip_bfloat16* __restrict__ Bt,
    void* __restrict__ Cv, const float* __restrict__ bias,
    const float* __restrict__ rowscale, float* __restrict__ stats,
    int Nr, int K, int F) {
  gemm_body<TN, OMODE>(A, Bt, Cv, bias, rowscale, stats, Nr, K, F,
                       (int)blockIdx.x, (int)blockIdx.y);
}

// ===== fat kernel: GEMM1 (blocks [0,G1)) || atomic-free scatter (blocks [G1,...)) ====
__global__ __launch_bounds__(256) void gemm1_scatter_kernel(
    const __hip_bfloat16* __restrict__ A, const __hip_bfloat16* __restrict__ Bt,
    void* __restrict__ Cv, const float* __restrict__ rowscale,
    int Nr, int K, int F, int G1,
    const int* __restrict__ src, const int* __restrict__ dst,
    const int* __restrict__ rowstart, const int* __restrict__ rank,
    int* __restrict__ csr_src, int E) {
  int b = (int)blockIdx.x;
  if (b < G1) {
    gemm_body<128, 1>(A, Bt, Cv, nullptr, rowscale, nullptr, Nr, K, F, b, 0);
  } else {
    int e = (b - G1) * 256 + (int)threadIdx.x;
    if (e < E) csr_src[rowstart[dst[e]] + rank[e]] = src[e];
  }
}

// ================= aggregation (persistent grid-stride, fused BN-stats) =========
// Ts rows pre-scaled by dis[row]. agg[d] = dis[d]*(Ts[d] + sum Ts[src]) (+bias).
// OMODE 0: bf16 out (L2 pre-agg).  OMODE 1: fp32 out + bias + fused relu-stats.
// 16-deep branchless gather batches (clamped index + select) for deep MLP.
template <int VEC, int OMODE>
__global__ __launch_bounds__(256) void agg_kernel(
    const __hip_bfloat16* __restrict__ Ts, const int* __restrict__ rowstart,
    const int* __restrict__ csr_src, const float* __restrict__ dis,
    const float* __restrict__ bias, void* __restrict__ H,
    float* __restrict__ stats, int Nn, int F) {
  __shared__ float lsum[512], lqs[512];
  int tid = (int)threadIdx.x;
  int wid4 = tid >> 6;
  int lane = tid & 63;
  int off = lane * VEC;
  const unsigned short* Tu = (const unsigned short*)Ts;

  float bj[VEC];
  float s[VEC], q[VEC];
#pragma unroll
  for (int j = 0; j < VEC; ++j) {
    bj[j] = (OMODE == 1) ? bias[off + j] : 0.f;
    s[j] = 0.f; q[j] = 0.f;
  }

  for (int d = blockIdx.x * 4 + wid4; d < Nn; d += gridDim.x * 4) {
    float acc[VEC];
    {  // self term (pre-scaled row)
      unsigned short r[VEC];
      if constexpr (VEC == 2) *(ushort2*)r = *(const ushort2*)&Tu[(size_t)d * F + off];
      else                    r[0] = Tu[(size_t)d * F + off];
#pragma unroll
      for (int j = 0; j < VEC; ++j) acc[j] = bfu2f(r[j]);
    }

    int e0 = rowstart[d], e1 = rowstart[d + 1];
    for (int e = e0; e < e1; e += 16) {
      int idx[16];
      bool val[16];
#pragma unroll
      for (int p = 0; p < 16; ++p) {
        int ee = e + p;
        val[p] = ee < e1;
        idx[p] = csr_src[val[p] ? ee : e1 - 1];
      }
      unsigned short r[16][VEC];
#pragma unroll
      for (int p = 0; p < 16; ++p) {
        if constexpr (VEC == 2) *(ushort2*)r[p] = *(const ushort2*)&Tu[(size_t)idx[p] * F + off];
        else                    r[p][0] = Tu[(size_t)idx[p] * F + off];
      }
#pragma unroll
      for (int p = 0; p < 16; ++p)
#pragma unroll
        for (int j = 0; j < VEC; ++j) acc[j] += val[p] ? bfu2f(r[p][j]) : 0.f;
    }

    float dd = dis[d];
    if constexpr (OMODE == 0) {
      union { ushort2 u; __hip_bfloat16 h[2]; } pk;
      if constexpr (VEC == 2) {
        pk.h[0] = __float2bfloat16(acc[0] * dd);
        pk.h[1] = __float2bfloat16(acc[1] * dd);
        *(ushort2*)&((__hip_bfloat16*)H)[(size_t)d * F + off] = pk.u;
      } else {
        ((__hip_bfloat16*)H)[(size_t)d * F + off] = __float2bfloat16(acc[0] * dd);
      }
    } else {
      float v[VEC];
#pragma unroll
      for (int j = 0; j < VEC; ++j) {
        v[j] = acc[j] * dd + bj[j];
        float rl = fmaxf(v[j], 0.f);
        s[j] += rl;
        q[j] += rl * rl;
      }
      if constexpr (VEC == 2) {
        *(float2*)&((float*)H)[(size_t)d * F + off] = make_float2(v[0], v[1]);
      } else {
        ((float*)H)[(size_t)d * F + off] = v[0];
      }
    }
  }

  if constexpr (OMODE == 1) {
#pragma unroll
    for (int j = 0; j < VEC; ++j) {
      lsum[(lane * VEC + j) * 4 + wid4] = s[j];
      lqs[(lane * VEC + j) * 4 + wid4] = q[j];
    }
    __syncthreads();
    int nc = 64 * VEC;  // == F
    for (int c = tid; c < nc; c += 256) {
      float a = lsum[c * 4 + 0] + lsum[c * 4 + 1] + lsum[c * 4 + 2] + lsum[c * 4 + 3];
      float b = lqs[c * 4 + 0] + lqs[c * 4 + 1] + lqs[c * 4 + 2] + lqs[c * 4 + 3];
      atomicAdd(&stats[c], a);
      atomicAdd(&stats[256 + c], b);
    }
  }
}

// ================= relu+BN apply (ss computed per-block from stats in LDS) =========
// fp32 -> bf16; optional rowscale (pre-scale for a following agg)
__global__ __launch_bounds__(256) void bnapply_kernel(
    const float* __restrict__ H, const float* __restrict__ stats,
    const float* __restrict__ g, const float* __restrict__ beta,
    const float* __restrict__ rowscale, __hip_bfloat16* __restrict__ O,
    size_t total4, int F, int logF, float invN) {
  __shared__ float ssc[256], ssb[256];
  int tid = (int)threadIdx.x;
  if (tid < F) {
    float mean = stats[tid] * invN;
    float var = stats[256 + tid] * invN - mean * mean;
    float sc = g[tid] * rsqrtf(var + EPS_BN);
    ssc[tid] = sc;
    ssb[tid] = beta[tid] - mean * sc;
  }
  __syncthreads();
  size_t i = (size_t)blockIdx.x * blockDim.x + tid;
  size_t stride = (size_t)gridDim.x * blockDim.x;
  for (; i < total4; i += stride) {
    size_t b = i * 4;
    float4 v = *(const float4*)&H[b];
    int c = (int)(b & (size_t)(F - 1));
    float rs = rowscale ? rowscale[b >> logF] : 1.0f;
    union { ushort4 u; __hip_bfloat16 h[4]; } pk;
    pk.h[0] = __float2bfloat16((fmaxf(v.x, 0.f) * ssc[c + 0] + ssb[c + 0]) * rs);
    pk.h[1] = __float2bfloat16((fmaxf(v.y, 0.f) * ssc[c + 1] + ssb[c + 1]) * rs);
    pk.h[2] = __float2bfloat16((fmaxf(v.z, 0.f) * ssc[c + 2] + ssb[c + 2]) * rs);
    pk.h[3] = __float2bfloat16((fmaxf(v.w, 0.f) * ssc[c + 3] + ssb[c + 3]) * rs);
    *(ushort4*)&O[b] = pk.u;
  }
}

// ================= fused L4 BN-apply + classifier =================
// one wave per row: h = BN(relu(Hf[row,:64])) in fp32; out[row,c] = h . Wc[:,c] + bc
__global__ __launch_bounds__(256) void bnapply_cls_kernel(
    const float* __restrict__ Hf, const float* __restrict__ stats,
    const float* __restrict__ g, const float* __restrict__ beta,
    const float* __restrict__ Wc, const float* __restrict__ bc,
    float* __restrict__ out, int Nn, float invN) {
  __shared__ float ssc[64], ssb[64];
  int tid = (int)threadIdx.x;
  if (tid < 64) {
    float mean = stats[tid] * invN;
    float var = stats[256 + tid] * invN - mean * mean;
    float sc = g[tid] * rsqrtf(var + EPS_BN);
    ssc[tid] = sc;
    ssb[tid] = beta[tid] - mean * sc;
  }
  __syncthreads();
  int gt = blockIdx.x * blockDim.x + tid;
  int wid = gt >> 6;
  int lane = tid & 63;
  if (wid >= Nn) return;
  float v = Hf[(size_t)wid * 64 + lane];
  float h = fmaxf(v, 0.f) * ssc[lane] + ssb[lane];
#pragma unroll
  for (int c = 0; c < 10; ++c) {
    float p = h * Wc[lane * 10 + c];
#pragma unroll
    for (int off = 32; off > 0; off >>= 1) p += __shfl_down(p, off, 64);
    if (lane == 0) out[(size_t)wid * 10 + c] = p + bc[c];
  }
}

// ================= host launch =================

extern "C" void kernel_launch(void* const* d_in, const int* in_sizes, int n_in,
                              void* d_out, int out_size, void* d_ws, size_t ws_size,
                              hipStream_t stream) {
  (void)n_in; (void)out_size; (void)ws_size;
  const float* x    = (const float*)d_in[0];
  const int*   edge = (const int*)d_in[1];
  const int E  = in_sizes[1] / 2;
  const int Nn = in_sizes[0] / 512;
  const int* e_src = edge;
  const int* e_dst = edge + E;

  const float* W[4]  = {(const float*)d_in[2],  (const float*)d_in[6],
                        (const float*)d_in[10], (const float*)d_in[14]};
  const float* bv[4] = {(const float*)d_in[3],  (const float*)d_in[7],
                        (const float*)d_in[11], (const float*)d_in[15]};
  const float* gv[4] = {(const float*)d_in[4],  (const float*)d_in[8],
                        (const float*)d_in[12], (const float*)d_in[16]};
  const float* bt[4] = {(const float*)d_in[5],  (const float*)d_in[9],
                        (const float*)d_in[13], (const float*)d_in[17]};
  const float* Wc = (const float*)d_in[18];
  const float* bc = (const float*)d_in[19];
  float* out = (float*)d_out;

  const int Kdim[4] = {512, 128, 256, 128};
  const int Fdim[4] = {128, 256, 128, 64};
  const float invN = 1.0f / (float)Nn;

  char* p = (char*)d_ws;
  auto alloc = [&](size_t bytes) -> void* {
    void* r = (void*)p;
    p += (bytes + 255) & ~(size_t)255;
    return r;
  };
  // cnt + stats adjacent -> single memset covers both
  int*   cnt      = (int*)alloc((size_t)Nn * 4);
  float* stats    = (float*)alloc(2048 * 4);   // 4 layers x 512 (sum | sumsq)
  size_t zeroBytes = (size_t)(((size_t)Nn * 4 + 255) & ~(size_t)255) + 2048 * 4;
  int*   rowstart = (int*)alloc((size_t)(Nn + 1) * 4);
  int*   bsum     = (int*)alloc(1024 * 4);
  float* dis      = (float*)alloc((size_t)Nn * 4);
  int*   rank     = (int*)alloc((size_t)E * 4);
  int*   csr_src  = (int*)alloc((size_t)E * 4);
  __hip_bfloat16* Wt[4];
  for (int l = 0; l < 4; ++l)
    Wt[l] = (__hip_bfloat16*)alloc((size_t)Kdim[l] * Fdim[l] * 2);
  // R0: x_bf16 [Nn*512]*2B during GEMM1, then reused as fp32 H [Nn*256]*4B
  char* R0 = (char*)alloc((size_t)Nn * 512 * 2);
  __hip_bfloat16* Tb = (__hip_bfloat16*)alloc((size_t)Nn * 256 * 2);
  __hip_bfloat16* P0 = (__hip_bfloat16*)alloc((size_t)Nn * 256 * 2);
  __hip_bfloat16* P1 = (__hip_bfloat16*)alloc((size_t)Nn * 256 * 2);
  __hip_bfloat16* Xb = (__hip_bfloat16*)R0;
  float*          Hf = (float*)R0;

  hipMemsetAsync(cnt, 0, zeroBytes, stream);

  // ---- fat prep: count_ticket || convert_bf16 || wtrans
  const int CB = (E + 255) / 256;
  const int VB = 2048;
  const int WB = (139264 + 255) / 256;
  prep_fat_kernel<<<CB + VB + WB, 256, 0, stream>>>(
      e_dst, cnt, rank, E, CB,
      x, Xb, (size_t)Nn * 512 / 4, VB,
      W[0], W[1], W[2], W[3], Wt[0], Wt[1], Wt[2], Wt[3]);

  int nb = (Nn + 1023) / 1024;
  scan1_kernel<<<nb, 1024, 0, stream>>>(cnt, rowstart, bsum, dis, Nn);
  scan2_kernel<<<1, 1024, 0, stream>>>(bsum, nb);
  scan3_kernel<<<nb, 1024, 0, stream>>>(rowstart, bsum, Nn, E);

  const int AGG_BLOCKS = 1536;  // 4 nodes/block-pass, 24 waves/CU
  int gx = (Nn + 127) / 128;

  // ---- L1: [GEMM(Xb[512] -> Tb[128] * dis)  ||  scatter] ; agg+b1+stats0 -> Hf
  gemm1_scatter_kernel<<<gx + CB, 256, 0, stream>>>(
      Xb, Wt[0], Tb, dis, Nn, 512, 128, gx,
      e_src, e_dst, rowstart, rank, csr_src, E);
  agg_kernel<2, 1><<<AGG_BLOCKS, 256, 0, stream>>>(Tb, rowstart, csr_src, dis,
                                                   bv[0], Hf, stats, Nn, 128);
  bnapply_kernel<<<(int)(((size_t)Nn * 128 / 4 + 255) / 256), 256, 0, stream>>>(
      Hf, stats, gv[0], bt[0], dis, P0, (size_t)Nn * 128 / 4, 128, 7, invN);

  // ---- L2 (swapped): agg(P0[128]) -> Tb bf16; GEMM+b2+stats1 -> Hf[256]; BN -> P1
  agg_kernel<2, 0><<<AGG_BLOCKS, 256, 0, stream>>>(P0, rowstart, csr_src, dis,
                                                   nullptr, Tb, nullptr, Nn, 128);
  {
    dim3 g(gx, 2);
    mfma_gemm_kernel<128, 2><<<g, 256, 0, stream>>>(Tb, Wt[1], Hf, bv[1], nullptr,
                                                    stats + 512, Nn, 128, 256);
  }
  bnapply_kernel<<<(int)(((size_t)Nn * 256 / 4 + 255) / 256), 256, 0, stream>>>(
      Hf, stats + 512, gv[1], bt[1], nullptr, P1, (size_t)Nn * 256 / 4, 256, 8, invN);

  // ---- L3: GEMM(P1[256] -> Tb[128] * dis); agg+b3+stats2 -> Hf; BN -> P0
  {
    dim3 g(gx, 1);
    mfma_gemm_kernel<128, 1><<<g, 256, 0, stream>>>(P1, Wt[2], Tb, nullptr, dis, nullptr,
                                                    Nn, 256, 128);
  }
  agg_kernel<2, 1><<<AGG_BLOCKS, 256, 0, stream>>>(Tb, rowstart, csr_src, dis,
                                                   bv[2], Hf, stats + 1024, Nn, 128);
  bnapply_kernel<<<(int)(((size_t)Nn * 128 / 4 + 255) / 256), 256, 0, stream>>>(
      Hf, stats + 1024, gv[2], bt[2], nullptr, P0, (size_t)Nn * 128 / 4, 128, 7, invN);

  // ---- L4: GEMM(P0[128] -> Tb[64] * dis); agg+b4+stats3 -> Hf; fused BN+cls -> out
  {
    dim3 g(gx, 1);
    mfma_gemm_kernel<64, 1><<<g, 256, 0, stream>>>(P0, Wt[3], Tb, nullptr, dis, nullptr,
                                                   Nn, 128, 64);
  }
  agg_kernel<1, 1><<<AGG_BLOCKS, 256, 0, stream>>>(Tb, rowstart, csr_src, dis,
                                                   bv[3], Hf, stats + 1536, Nn, 64);
  int clsBlocks = (Nn * 64 + 255) / 256;
  bnapply_cls_kernel<<<clsBlocks, 256, 0, stream>>>(Hf, stats + 1536, gv[3], bt[3],
                                                    Wc, bc, out, Nn, invN);
}

// Round 7
// 950.019 us; speedup vs baseline: 2.3555x; 1.0951x over previous
//
#include <hip/hip_runtime.h>
#include <hip/hip_bf16.h>

#define EPS_BN 1e-5f

using frag8 = __attribute__((ext_vector_type(8))) short;   // 8 bf16 (4 VGPRs)
using f32x4 = __attribute__((ext_vector_type(4))) float;   // 4 fp32 acc

typedef const __attribute__((address_space(1))) void* gas_ptr;
typedef __attribute__((address_space(3))) void* las_ptr;

__device__ __forceinline__ void async_ld16(const void* g, void* l) {
  __builtin_amdgcn_global_load_lds((gas_ptr)g, (las_ptr)l, 16, 0, 0);
}

__device__ __forceinline__ float bfu2f(unsigned short u) {
  union { unsigned int i; float f; } c;
  c.i = (unsigned int)u << 16;
  return c.f;
}

// ================= small prep =================

// Wt0[f][k] = bf16(W1[k][f])   (needed before fat1's GEMM)
__global__ void wtrans1_kernel(const float* __restrict__ W1, __hip_bfloat16* __restrict__ T) {
  int i = blockIdx.x * blockDim.x + threadIdx.x;
  if (i < 512 * 128) {
    int k = i / 128, f = i % 128;
    T[f * 512 + k] = __float2bfloat16(W1[i]);
  }
}

// ================= hierarchical exclusive scan (+ dis = rsqrt(deg)) =================
__global__ void scan1_kernel(const int* __restrict__ cnt, int* __restrict__ out,
                             int* __restrict__ bsum, float* __restrict__ dis, int n) {
  __shared__ int sdata[1024];
  int tid = threadIdx.x;
  int i = blockIdx.x * 1024 + tid;
  int v = (i < n) ? cnt[i] : 0;
  if (i < n) dis[i] = rsqrtf((float)v + 1.0f);
  sdata[tid] = v;
  __syncthreads();
  for (int off = 1; off < 1024; off <<= 1) {
    int t = (tid >= off) ? sdata[tid - off] : 0;
    __syncthreads();
    sdata[tid] += t;
    __syncthreads();
  }
  if (i < n) out[i] = sdata[tid] - v;
  if (tid == 1023) bsum[blockIdx.x] = sdata[1023];
}

__global__ void scan2_kernel(int* __restrict__ bsum, int nb) {
  __shared__ int sdata[1024];
  int tid = threadIdx.x;
  int v = (tid < nb) ? bsum[tid] : 0;
  sdata[tid] = v;
  __syncthreads();
  for (int off = 1; off < 1024; off <<= 1) {
    int t = (tid >= off) ? sdata[tid - off] : 0;
    __syncthreads();
    sdata[tid] += t;
    __syncthreads();
  }
  if (tid < nb) bsum[tid] = sdata[tid] - v;
}

__global__ void scan3_kernel(int* __restrict__ out, const int* __restrict__ bsum,
                             int n, int E) {
  int i = blockIdx.x * 1024 + threadIdx.x;
  if (i < n) out[i] += bsum[blockIdx.x];
  if (i == 0) out[n] = E;
}

// ================= bf16 MFMA GEMM body: C[Nr,F] = A[Nr,K] @ Bt[F,K]^T ===========
// ASTAGE 0: A bf16 via global_load_lds
// ASTAGE 1: A fp32, VGPR staging + convert          (GEMM1 reads x directly)
// ASTAGE 2: A bf16 + BN affine from statsIn/g/beta  (GEMM3/GEMM4 fold prev BN)
// OMODE 0: bf16 out plain
// OMODE 1: bf16 out * rowscale[row]
// OMODE 3: bf16 out = relu(acc+bias[col]) + fused BN-stats accumulation
template <int TN, int ASTAGE, int OMODE>
__device__ __forceinline__ void gemm_body(
    const void* __restrict__ Ap, const __hip_bfloat16* __restrict__ Bt,
    __hip_bfloat16* __restrict__ C, const float* __restrict__ bias,
    const float* __restrict__ rowscale,
    const float* __restrict__ statsIn, const float* __restrict__ g,
    const float* __restrict__ beta, float* __restrict__ statsOut, float invN,
    int Nr, int K, int F, int bx, int by) {
  constexpr int WM = (TN == 128) ? 64 : 32;
  constexpr int MI = WM / 16;
  __shared__ __align__(16) __hip_bfloat16 As[128 * 32];
  __shared__ __align__(16) __hip_bfloat16 Bs[TN * 32];
  __shared__ float sacc[128], sqc[128];
  __shared__ float ssc[256], ssb[256];
  int tid = (int)threadIdx.x;
  int wid = tid >> 6, lane = tid & 63;
  int rowBase = bx * 128;
  int colBase = by * TN;
  int wr, wc;
  if (TN == 128) { wr = (wid >> 1) * 64; wc = (wid & 1) * 64; }
  else           { wr = wid * 32;        wc = 0; }

  f32x4 zero = {0.f, 0.f, 0.f, 0.f};
  f32x4 acc[MI][4];
#pragma unroll
  for (int i = 0; i < MI; ++i)
#pragma unroll
    for (int j = 0; j < 4; ++j) acc[i][j] = zero;

  int lm = lane & 15;
  int k8 = (lane >> 4) * 8;

  if constexpr (OMODE == 3) {
    if (tid < 128) { sacc[tid] = 0.f; sqc[tid] = 0.f; }
  }
  if constexpr (ASTAGE == 2) {
    for (int k = tid; k < K; k += 256) {
      float mean = statsIn[k] * invN;
      float var = statsIn[256 + k] * invN - mean * mean;
      float sc = g[k] * rsqrtf(var + EPS_BN);
      ssc[k] = sc;
      ssb[k] = beta[k] - mean * sc;
    }
    __syncthreads();
  }

  for (int k0 = 0; k0 < K; k0 += 32) {
    // ---- stage A tile [128 rows][32 k]
    if constexpr (ASTAGE == 0) {
#pragma unroll
      for (int p = 0; p < 2; ++p) {
        int sidx = p * 256 + tid;
        int row = sidx >> 2;
        int kq = (sidx & 3) * 8;
        int gr = rowBase + row;
        if (gr >= Nr) gr = Nr - 1;
        async_ld16((const __hip_bfloat16*)Ap + (size_t)gr * K + k0 + kq,
                   (char*)As + (p * 256 + wid * 64) * 16);
      }
    } else {
#pragma unroll
      for (int p = 0; p < 2; ++p) {
        int sidx = p * 256 + tid;
        int row = sidx >> 2;
        int kq = (sidx & 3) * 8;
        int gr = rowBase + row;
        if (gr >= Nr) gr = Nr - 1;
        union { frag8 f; __hip_bfloat16 h[8]; } pk;
        if constexpr (ASTAGE == 1) {
          const float* s = (const float*)Ap + (size_t)gr * K + k0 + kq;
          float4 a = *(const float4*)s;
          float4 b2 = *(const float4*)(s + 4);
          pk.h[0] = __float2bfloat16(a.x);  pk.h[1] = __float2bfloat16(a.y);
          pk.h[2] = __float2bfloat16(a.z);  pk.h[3] = __float2bfloat16(a.w);
          pk.h[4] = __float2bfloat16(b2.x); pk.h[5] = __float2bfloat16(b2.y);
          pk.h[6] = __float2bfloat16(b2.z); pk.h[7] = __float2bfloat16(b2.w);
        } else {
          const unsigned short* s = (const unsigned short*)Ap + (size_t)gr * K + k0 + kq;
          ushort4 a = *(const ushort4*)s;
          ushort4 b2 = *(const ushort4*)(s + 4);
          int kk = k0 + kq;
          pk.h[0] = __float2bfloat16(bfu2f(a.x)  * ssc[kk + 0] + ssb[kk + 0]);
          pk.h[1] = __float2bfloat16(bfu2f(a.y)  * ssc[kk + 1] + ssb[kk + 1]);
          pk.h[2] = __float2bfloat16(bfu2f(a.z)  * ssc[kk + 2] + ssb[kk + 2]);
          pk.h[3] = __float2bfloat16(bfu2f(a.w)  * ssc[kk + 3] + ssb[kk + 3]);
          pk.h[4] = __float2bfloat16(bfu2f(b2.x) * ssc[kk + 4] + ssb[kk + 4]);
          pk.h[5] = __float2bfloat16(bfu2f(b2.y) * ssc[kk + 5] + ssb[kk + 5]);
          pk.h[6] = __float2bfloat16(bfu2f(b2.z) * ssc[kk + 6] + ssb[kk + 6]);
          pk.h[7] = __float2bfloat16(bfu2f(b2.w) * ssc[kk + 7] + ssb[kk + 7]);
        }
        *(frag8*)&As[row * 32 + kq] = pk.f;
      }
    }
    // ---- stage B tile [TN cols][32 k] (always async bf16)
    constexpr int BPASS = TN / 64;
#pragma unroll
    for (int p = 0; p < BPASS; ++p) {
      int sidx = p * 256 + tid;
      int col = sidx >> 2;
      int kq = (sidx & 3) * 8;
      async_ld16(Bt + (size_t)(colBase + col) * K + k0 + kq,
                 (char*)Bs + (p * 256 + wid * 64) * 16);
    }
    __syncthreads();

    frag8 af[MI], bf[4];
#pragma unroll
    for (int i = 0; i < MI; ++i)
      af[i] = *(const frag8*)&As[(wr + i * 16 + lm) * 32 + k8];
#pragma unroll
    for (int j = 0; j < 4; ++j)
      bf[j] = *(const frag8*)&Bs[(wc + j * 16 + lm) * 32 + k8];
#pragma unroll
    for (int i = 0; i < MI; ++i)
#pragma unroll
      for (int j = 0; j < 4; ++j)
        acc[i][j] = __builtin_amdgcn_mfma_f32_16x16x32_bf16(af[i], bf[j], acc[i][j], 0, 0, 0);
    __syncthreads();
  }

  // C/D layout: col=lane&15, row=(lane>>4)*4+reg  [verified m89]
  int rquad = (lane >> 4) * 4;
  float s[4] = {0.f, 0.f, 0.f, 0.f}, q[4] = {0.f, 0.f, 0.f, 0.f};
#pragma unroll
  for (int i = 0; i < MI; ++i) {
    int rb = rowBase + wr + i * 16 + rquad;
#pragma unroll
    for (int r = 0; r < 4; ++r) {
      int row = rb + r;
      if (row < Nr) {
        if constexpr (OMODE == 0) {
#pragma unroll
          for (int j = 0; j < 4; ++j) {
            int col = colBase + wc + j * 16 + lm;
            C[(size_t)row * F + col] = __float2bfloat16(acc[i][j][r]);
          }
        } else if constexpr (OMODE == 1) {
          float rs = rowscale[row];
#pragma unroll
          for (int j = 0; j < 4; ++j) {
            int col = colBase + wc + j * 16 + lm;
            C[(size_t)row * F + col] = __float2bfloat16(acc[i][j][r] * rs);
          }
        } else {  // OMODE 3: relu + stats, bf16 out
#pragma unroll
          for (int j = 0; j < 4; ++j) {
            int col = colBase + wc + j * 16 + lm;
            float v = acc[i][j][r] + bias[col];
            float rl = fmaxf(v, 0.f);
            C[(size_t)row * F + col] = __float2bfloat16(rl);
            s[j] += rl;
            q[j] += rl * rl;
          }
        }
      }
    }
  }

  if constexpr (OMODE == 3) {
#pragma unroll
    for (int j = 0; j < 4; ++j) {
      s[j] += __shfl_xor(s[j], 16, 64); s[j] += __shfl_xor(s[j], 32, 64);
      q[j] += __shfl_xor(q[j], 16, 64); q[j] += __shfl_xor(q[j], 32, 64);
    }
    if (lane < 16) {
#pragma unroll
      for (int j = 0; j < 4; ++j) {
        atomicAdd(&sacc[wc + j * 16 + lane], s[j]);
        atomicAdd(&sqc[wc + j * 16 + lane], q[j]);
      }
    }
    __syncthreads();
    if (tid < 128) {
      atomicAdd(&statsOut[colBase + tid], sacc[tid]);
      atomicAdd(&statsOut[256 + colBase + tid], sqc[tid]);
    }
  }
}

// ===== fat1: GEMM1 (fp32 A = x, B = Wt0) || ticket-count || wtrans(W2..W4) =====
__global__ __launch_bounds__(256) void fat1_kernel(
    const float* __restrict__ x, const __hip_bfloat16* __restrict__ Wt0,
    __hip_bfloat16* __restrict__ T1, int Nn, int G1,
    const int* __restrict__ e_dst, int* __restrict__ cnt, int* __restrict__ rank,
    int E, int CB,
    const float* __restrict__ W2, const float* __restrict__ W3, const float* __restrict__ W4,
    __hip_bfloat16* __restrict__ Tw2, __hip_bfloat16* __restrict__ Tw3,
    __hip_bfloat16* __restrict__ Tw4) {
  int b = (int)blockIdx.x;
  if (b < G1) {
    gemm_body<128, 1, 0>(x, Wt0, T1, nullptr, nullptr, nullptr, nullptr, nullptr,
                         nullptr, 0.f, Nn, 512, 128, b, 0);
  } else if (b < G1 + CB) {
    int e = (b - G1) * 256 + (int)threadIdx.x;
    if (e < E) rank[e] = atomicAdd(&cnt[e_dst[e]], 1);
  } else {
    int i = (b - G1 - CB) * 256 + (int)threadIdx.x;
    const float* W; __hip_bfloat16* T; int K, F, base;
    if (i < 32768)       { W = W2; T = Tw2; K = 128; F = 256; base = 0; }
    else if (i < 65536)  { W = W3; T = Tw3; K = 256; F = 128; base = 32768; }
    else if (i < 73728)  { W = W4; T = Tw4; K = 128; F = 64;  base = 65536; }
    else return;
    int j = i - base;
    int k = j / F, f = j % F;
    T[f * K + k] = __float2bfloat16(W[j]);
  }
}

template <int TN, int ASTAGE, int OMODE>
__global__ __launch_bounds__(256) void mfma_gemm_kernel(
    const void* __restrict__ A, const __hip_bfloat16* __restrict__ Bt,
    __hip_bfloat16* __restrict__ C, const float* __restrict__ bias,
    const float* __restrict__ rowscale, const float* __restrict__ statsIn,
    const float* __restrict__ g, const float* __restrict__ beta,
    float* __restrict__ statsOut, float invN, int Nr, int K, int F) {
  gemm_body<TN, ASTAGE, OMODE>(A, Bt, C, bias, rowscale, statsIn, g, beta, statsOut,
                               invN, Nr, K, F, (int)blockIdx.x, (int)blockIdx.y);
}

// ===== fat2: atomic-free scatter || T1 *= dis[row] (in-place bf16) =====
__global__ __launch_bounds__(256) void fat2_kernel(
    const int* __restrict__ src, const int* __restrict__ dst,
    const int* __restrict__ rowstart, const int* __restrict__ rank,
    int* __restrict__ csr_src, int E, int SB,
    __hip_bfloat16* __restrict__ T1, const float* __restrict__ dis, int n8) {
  int b = (int)blockIdx.x;
  if (b < SB) {
    int e = b * 256 + (int)threadIdx.x;
    if (e < E) csr_src[rowstart[dst[e]] + rank[e]] = src[e];
  } else {
    int i = (b - SB) * 256 + (int)threadIdx.x;
    if (i < n8) {
      float dd = dis[i >> 4];  // 16 threads per 128-feature row
      unsigned short* p8 = (unsigned short*)T1 + (size_t)i * 8;
      ushort4 a = *(ushort4*)p8;
      ushort4 c = *(ushort4*)(p8 + 4);
      union { ushort4 u; __hip_bfloat16 h[4]; } o0, o1;
      o0.h[0] = __float2bfloat16(bfu2f(a.x) * dd);
      o0.h[1] = __float2bfloat16(bfu2f(a.y) * dd);
      o0.h[2] = __float2bfloat16(bfu2f(a.z) * dd);
      o0.h[3] = __float2bfloat16(bfu2f(a.w) * dd);
      o1.h[0] = __float2bfloat16(bfu2f(c.x) * dd);
      o1.h[1] = __float2bfloat16(bfu2f(c.y) * dd);
      o1.h[2] = __float2bfloat16(bfu2f(c.z) * dd);
      o1.h[3] = __float2bfloat16(bfu2f(c.w) * dd);
      *(ushort4*)p8 = o0.u;
      *(ushort4*)(p8 + 4) = o1.u;
    }
  }
}

// ================= aggregation (persistent grid-stride) =================
// Ts rows pre-scaled by dis[row]; acc = Ts[d] + sum_src Ts[src]; 16-deep batches.
// AMODE 1 (L1): H=dis*acc+bias; stats; R = bf16(relu(H)*dis); sd[d]=dis[d]+sum dis[s]
// AMODE 2 (L2 pre): out = bf16(dis*(ssc[c]*acc + ssb[c]*sd[d]))  (folds BN1)
// AMODE 3 (L3): H=dis*acc+bias; stats; R = bf16(relu(H))
// AMODE 4 (L4): H=dis*acc+bias; stats; R = fp32 relu(H)
template <int VEC, int AMODE>
__global__ __launch_bounds__(256) void agg_kernel(
    const __hip_bfloat16* __restrict__ Ts, const int* __restrict__ rowstart,
    const int* __restrict__ csr_src, const float* __restrict__ dis,
    const float* __restrict__ bias, void* __restrict__ H,
    float* __restrict__ stats, const float* __restrict__ statsIn,
    const float* __restrict__ g, const float* __restrict__ beta,
    float* __restrict__ sd, float invN, int Nn, int F) {
  __shared__ float lsum[512], lqs[512];
  __shared__ float ssc[128], ssb[128];
  int tid = (int)threadIdx.x;
  int wid4 = tid >> 6;
  int lane = tid & 63;
  int off = lane * VEC;
  const unsigned short* Tu = (const unsigned short*)Ts;

  if constexpr (AMODE == 2) {
    if (tid < F) {
      float mean = statsIn[tid] * invN;
      float var = statsIn[256 + tid] * invN - mean * mean;
      float sc = g[tid] * rsqrtf(var + EPS_BN);
      ssc[tid] = sc;
      ssb[tid] = beta[tid] - mean * sc;
    }
    __syncthreads();
  }

  float bj[VEC];
  float s[VEC], q[VEC];
#pragma unroll
  for (int j = 0; j < VEC; ++j) {
    bj[j] = (AMODE == 1 || AMODE == 3 || AMODE == 4) ? bias[off + j] : 0.f;
    s[j] = 0.f; q[j] = 0.f;
  }

  for (int d = blockIdx.x * 4 + wid4; d < Nn; d += gridDim.x * 4) {
    float acc[VEC];
    {  // self term (pre-scaled row)
      unsigned short r[VEC];
      if constexpr (VEC == 2) *(ushort2*)r = *(const ushort2*)&Tu[(size_t)d * F + off];
      else                    r[0] = Tu[(size_t)d * F + off];
#pragma unroll
      for (int j = 0; j < VEC; ++j) acc[j] = bfu2f(r[j]);
    }
    float dd = dis[d];
    float sdacc = dd;

    int e0 = rowstart[d], e1 = rowstart[d + 1];
    for (int e = e0; e < e1; e += 16) {
      int idx[16];
      bool val[16];
#pragma unroll
      for (int p = 0; p < 16; ++p) {
        int ee = e + p;
        val[p] = ee < e1;
        idx[p] = csr_src[val[p] ? ee : e1 - 1];
      }
      unsigned short r[16][VEC];
      float dv[16];
#pragma unroll
      for (int p = 0; p < 16; ++p) {
        if constexpr (VEC == 2) *(ushort2*)r[p] = *(const ushort2*)&Tu[(size_t)idx[p] * F + off];
        else                    r[p][0] = Tu[(size_t)idx[p] * F + off];
        if constexpr (AMODE == 1) dv[p] = dis[idx[p]];
      }
#pragma unroll
      for (int p = 0; p < 16; ++p) {
#pragma unroll
        for (int j = 0; j < VEC; ++j) acc[j] += val[p] ? bfu2f(r[p][j]) : 0.f;
        if constexpr (AMODE == 1) sdacc += val[p] ? dv[p] : 0.f;
      }
    }

    if constexpr (AMODE == 2) {
      float sdv = sd[d];
      union { ushort2 u; __hip_bfloat16 h[2]; } pk;
      pk.h[0] = __float2bfloat16(dd * (ssc[off + 0] * acc[0] + ssb[off + 0] * sdv));
      pk.h[1] = __float2bfloat16(dd * (ssc[off + 1] * acc[1] + ssb[off + 1] * sdv));
      *(ushort2*)&((__hip_bfloat16*)H)[(size_t)d * F + off] = pk.u;
    } else {
      float rl[VEC];
#pragma unroll
      for (int j = 0; j < VEC; ++j) {
        float v = acc[j] * dd + bj[j];
        rl[j] = fmaxf(v, 0.f);
        s[j] += rl[j];
        q[j] += rl[j] * rl[j];
      }
      if constexpr (AMODE == 1) {
        union { ushort2 u; __hip_bfloat16 h[2]; } pk;
        pk.h[0] = __float2bfloat16(rl[0] * dd);
        pk.h[1] = __float2bfloat16(rl[1] * dd);
        *(ushort2*)&((__hip_bfloat16*)H)[(size_t)d * F + off] = pk.u;
        if (lane == 0) sd[d] = sdacc;
      } else if constexpr (AMODE == 3) {
        union { ushort2 u; __hip_bfloat16 h[2]; } pk;
        pk.h[0] = __float2bfloat16(rl[0]);
        pk.h[1] = __float2bfloat16(rl[1]);
        *(ushort2*)&((__hip_bfloat16*)H)[(size_t)d * F + off] = pk.u;
      } else {  // AMODE 4, VEC==1, fp32 out
        ((float*)H)[(size_t)d * F + off] = rl[0];
      }
    }
  }

  if constexpr (AMODE != 2) {
#pragma unroll
    for (int j = 0; j < VEC; ++j) {
      lsum[(lane * VEC + j) * 4 + wid4] = s[j];
      lqs[(lane * VEC + j) * 4 + wid4] = q[j];
    }
    __syncthreads();
    int nc = 64 * VEC;  // == F
    for (int c = tid; c < nc; c += 256) {
      float a = lsum[c * 4 + 0] + lsum[c * 4 + 1] + lsum[c * 4 + 2] + lsum[c * 4 + 3];
      float b = lqs[c * 4 + 0] + lqs[c * 4 + 1] + lqs[c * 4 + 2] + lqs[c * 4 + 3];
      atomicAdd(&stats[c], a);
      atomicAdd(&stats[256 + c], b);
    }
  }
}

// ================= fused L4 BN-apply + classifier =================
// input R4 already relu'd (fp32); one wave per row.
__global__ __launch_bounds__(256) void bnapply_cls_kernel(
    const float* __restrict__ R4, const float* __restrict__ stats,
    const float* __restrict__ g, const float* __restrict__ beta,
    const float* __restrict__ Wc, const float* __restrict__ bc,
    float* __restrict__ out, int Nn, float invN) {
  __shared__ float ssc[64], ssb[64];
  int tid = (int)threadIdx.x;
  if (tid < 64) {
    float mean = stats[tid] * invN;
    float var = stats[256 + tid] * invN - mean * mean;
    float sc = g[tid] * rsqrtf(var + EPS_BN);
    ssc[tid] = sc;
    ssb[tid] = beta[tid] - mean * sc;
  }
  __syncthreads();
  int gt = blockIdx.x * blockDim.x + tid;
  int wid = gt >> 6;
  int lane = tid & 63;
  if (wid >= Nn) return;
  float v = R4[(size_t)wid * 64 + lane];
  float h = v * ssc[lane] + ssb[lane];
#pragma unroll
  for (int c = 0; c < 10; ++c) {
    float p = h * Wc[lane * 10 + c];
#pragma unroll
    for (int off = 32; off > 0; off >>= 1) p += __shfl_down(p, off, 64);
    if (lane == 0) out[(size_t)wid * 10 + c] = p + bc[c];
  }
}

// ================= host launch =================

extern "C" void kernel_launch(void* const* d_in, const int* in_sizes, int n_in,
                              void* d_out, int out_size, void* d_ws, size_t ws_size,
                              hipStream_t stream) {
  (void)n_in; (void)out_size; (void)ws_size;
  const float* x    = (const float*)d_in[0];
  const int*   edge = (const int*)d_in[1];
  const int E  = in_sizes[1] / 2;
  const int Nn = in_sizes[0] / 512;
  const int* e_src = edge;
  const int* e_dst = edge + E;

  const float* W[4]  = {(const float*)d_in[2],  (const float*)d_in[6],
                        (const float*)d_in[10], (const float*)d_in[14]};
  const float* bv[4] = {(const float*)d_in[3],  (const float*)d_in[7],
                        (const float*)d_in[11], (const float*)d_in[15]};
  const float* gv[4] = {(const float*)d_in[4],  (const float*)d_in[8],
                        (const float*)d_in[12], (const float*)d_in[16]};
  const float* bt[4] = {(const float*)d_in[5],  (const float*)d_in[9],
                        (const float*)d_in[13], (const float*)d_in[17]};
  const float* Wc = (const float*)d_in[18];
  const float* bc = (const float*)d_in[19];
  float* out = (float*)d_out;

  const float invN = 1.0f / (float)Nn;

  char* p = (char*)d_ws;
  auto alloc = [&](size_t bytes) -> void* {
    void* r = (void*)p;
    p += (bytes + 255) & ~(size_t)255;
    return r;
  };
  // cnt + stats adjacent -> single memset covers both
  int*   cnt      = (int*)alloc((size_t)Nn * 4);
  float* stats    = (float*)alloc(2048 * 4);   // L1 | L2 | L3 | L4, each 512
  size_t zeroBytes = (size_t)(((size_t)Nn * 4 + 255) & ~(size_t)255) + 2048 * 4;
  int*   rowstart = (int*)alloc((size_t)(Nn + 1) * 4);
  int*   bsum     = (int*)alloc(1024 * 4);
  float* dis      = (float*)alloc((size_t)Nn * 4);
  float* sd       = (float*)alloc((size_t)Nn * 4);
  int*   rank     = (int*)alloc((size_t)E * 4);
  int*   csr_src  = (int*)alloc((size_t)E * 4);
  __hip_bfloat16* Wt0 = (__hip_bfloat16*)alloc(512 * 128 * 2);
  __hip_bfloat16* Wt1 = (__hip_bfloat16*)alloc(128 * 256 * 2);
  __hip_bfloat16* Wt2 = (__hip_bfloat16*)alloc(256 * 128 * 2);
  __hip_bfloat16* Wt3 = (__hip_bfloat16*)alloc(128 * 64 * 2);
  __hip_bfloat16* Ts1 = (__hip_bfloat16*)alloc((size_t)Nn * 128 * 2);
  __hip_bfloat16* R1  = (__hip_bfloat16*)alloc((size_t)Nn * 128 * 2);
  __hip_bfloat16* Tb2 = (__hip_bfloat16*)alloc((size_t)Nn * 128 * 2);
  __hip_bfloat16* R2  = (__hip_bfloat16*)alloc((size_t)Nn * 256 * 2);
  __hip_bfloat16* Ts3 = (__hip_bfloat16*)alloc((size_t)Nn * 128 * 2);
  __hip_bfloat16* R3  = (__hip_bfloat16*)alloc((size_t)Nn * 128 * 2);
  __hip_bfloat16* Ts4 = (__hip_bfloat16*)alloc((size_t)Nn * 64 * 2);
  float*          R4  = (float*)alloc((size_t)Nn * 64 * 4);

  hipMemsetAsync(cnt, 0, zeroBytes, stream);

  // Wt0 first (fat1's GEMM B operand)
  wtrans1_kernel<<<(512 * 128 + 255) / 256, 256, 0, stream>>>(W[0], Wt0);

  // ---- fat1: GEMM1 (x fp32 -> T1 bf16, unscaled) || ticket count || wtrans W2..W4
  const int gx = (Nn + 127) / 128;
  const int CB = (E + 255) / 256;
  const int WB = (73728 + 255) / 256;
  fat1_kernel<<<gx + CB + WB, 256, 0, stream>>>(
      x, Wt0, Ts1, Nn, gx, e_dst, cnt, rank, E, CB,
      W[1], W[2], W[3], Wt1, Wt2, Wt3);

  int nb = (Nn + 1023) / 1024;
  scan1_kernel<<<nb, 1024, 0, stream>>>(cnt, rowstart, bsum, dis, Nn);
  scan2_kernel<<<1, 1024, 0, stream>>>(bsum, nb);
  scan3_kernel<<<nb, 1024, 0, stream>>>(rowstart, bsum, Nn, E);

  // ---- fat2: scatter || Ts1 *= dis[row]
  int n8 = Nn * 128 / 8;
  int TB = (n8 + 255) / 256;
  fat2_kernel<<<CB + TB, 256, 0, stream>>>(e_src, e_dst, rowstart, rank, csr_src, E, CB,
                                           Ts1, dis, n8);

  const int AGG_BLOCKS = 2048;

  // ---- L1: agg(Ts1) -> R1 = relu(H1)*dis bf16, stats0, sd
  agg_kernel<2, 1><<<AGG_BLOCKS, 256, 0, stream>>>(
      Ts1, rowstart, csr_src, dis, bv[0], R1, stats, nullptr, nullptr, nullptr,
      sd, invN, Nn, 128);
  // ---- L2 pre-agg: agg(R1) -> Tb2 (BN1 folded)
  agg_kernel<2, 2><<<AGG_BLOCKS, 256, 0, stream>>>(
      R1, rowstart, csr_src, dis, nullptr, Tb2, nullptr, stats, gv[0], bt[0],
      sd, invN, Nn, 128);
  // ---- GEMM2: Tb2[128] -> R2 = relu(H2) bf16 [256], stats1
  {
    dim3 g(gx, 2);
    mfma_gemm_kernel<128, 0, 3><<<g, 256, 0, stream>>>(
        Tb2, Wt1, R2, bv[1], nullptr, nullptr, nullptr, nullptr, stats + 512, invN,
        Nn, 128, 256);
  }
  // ---- GEMM3: A = BN2(R2) via affine staging -> Ts3 = out*dis bf16 [128]
  {
    dim3 g(gx, 1);
    mfma_gemm_kernel<128, 2, 1><<<g, 256, 0, stream>>>(
        R2, Wt2, Ts3, nullptr, dis, stats + 512, gv[1], bt[1], nullptr, invN,
        Nn, 256, 128);
  }
  // ---- L3: agg(Ts3) -> R3 = relu(H3) bf16, stats2
  agg_kernel<2, 3><<<AGG_BLOCKS, 256, 0, stream>>>(
      Ts3, rowstart, csr_src, dis, bv[2], R3, stats + 1024, nullptr, nullptr, nullptr,
      nullptr, invN, Nn, 128);
  // ---- GEMM4: A = BN3(R3) via affine staging -> Ts4 = out*dis bf16 [64]
  {
    dim3 g(gx, 1);
    mfma_gemm_kernel<64, 2, 1><<<g, 256, 0, stream>>>(
        R3, Wt3, Ts4, nullptr, dis, stats + 1024, gv[2], bt[2], nullptr, invN,
        Nn, 128, 64);
  }
  // ---- L4: agg(Ts4) -> R4 = relu(H4) fp32, stats3
  agg_kernel<1, 4><<<AGG_BLOCKS, 256, 0, stream>>>(
      Ts4, rowstart, csr_src, dis, bv[3], R4, stats + 1536, nullptr, nullptr, nullptr,
      nullptr, invN, Nn, 64);
  // ---- BN4 + classifier
  int clsBlocks = (Nn * 64 + 255) / 256;
  bnapply_cls_kernel<<<clsBlocks, 256, 0, stream>>>(R4, stats + 1536, gv[3], bt[3],
                                                    Wc, bc, out, Nn, invN);
}